// Round 20
// baseline (407.643 us; speedup 1.0000x reference)
//
#include <hip/hip_runtime.h>
#include <hip/hip_bf16.h>
#include <math.h>

typedef unsigned short u16;
typedef unsigned int u32;
typedef __attribute__((ext_vector_type(8))) short bf16x8v;
typedef __attribute__((ext_vector_type(4))) float f32x4;

// ---------------- problem constants ----------------
constexpr int NS = 25, NQ = 15, NB = 40;
constexpr int B3 = 375;     // 15*25
constexpr int T49 = 49;
constexpr float BN_INV = 0.9999950000374997f;

// ---------------- workspace layout (BYTES) ----------------------------------
constexpr size_t A1H_OFF    = 0;
constexpr size_t A1L_OFF    = 8028160;
constexpr size_t X2_OFF     = 16056320;
constexpr size_t P2H_OFF    = 48168960;
constexpr size_t P2L_OFF    = 52183040;
constexpr size_t X3_OFF     = 0;
constexpr size_t P3H_OFF    = 56197120;
constexpr size_t P3L_OFF    = 58204160;
constexpr size_t X4_OFF     = 0;
constexpr size_t FEATTH_OFF = 60211200;
constexpr size_t FEATTL_OFF = 61214720;
constexpr size_t PROJ_OFF   = 0;
constexpr size_t ATTH_OFF   = 16056320;
constexpr size_t ATTL_OFF   = 25464320;
constexpr size_t GI_OFF     = 62218240;
constexpr size_t Y0H_OFF    = 0;
constexpr size_t Y0L_OFF    = 4704000;
constexpr size_t HFIN_OFF   = 90442240;
constexpr size_t WBH_OFF    = 91027456;
constexpr size_t WBL_OFF    = 92325888;
constexpr size_t W2_E = 0;
constexpr size_t W3_E = 18432;
constexpr size_t W4_E = 92160;
constexpr size_t AW_E = 387072;
constexpr size_t WI0_E = 403456;
constexpr size_t WI1_E = 600064;
constexpr int CVT_N = 649216;

static __device__ __forceinline__ u16 f2b(float f) {
  __hip_bfloat16 h = __float2bfloat16(f);
  return *reinterpret_cast<u16*>(&h);
}
static __device__ __forceinline__ float b2f(u16 u) {
  return __uint_as_float((u32)u << 16);
}
constexpr float LOG2E = 1.4426950408889634f;
static __device__ __forceinline__ float fsigmoid(float x) {
  return __builtin_amdgcn_rcpf(1.f + __builtin_amdgcn_exp2f(-x * LOG2E));
}
static __device__ __forceinline__ float ftanh(float x) {
  return 1.f - 2.f * __builtin_amdgcn_rcpf(__builtin_amdgcn_exp2f(x * (2.f * LOG2E)) + 1.f);
}
static __device__ __forceinline__ void split8(const float* v, u32* hp, u32* lp) {
  u16 h[8], l[8];
#pragma unroll
  for (int j = 0; j < 8; ++j) {
    const u16 hb = f2b(v[j]);
    h[j] = hb;
    l[j] = f2b(v[j] - b2f(hb));
  }
#pragma unroll
  for (int j = 0; j < 4; ++j) {
    hp[j] = (u32)h[2 * j] | ((u32)h[2 * j + 1] << 16);
    lp[j] = (u32)l[2 * j] | ((u32)l[2 * j + 1] << 16);
  }
}

// ---------------- fused weight converter (1 launch) ----------------
__global__ void cvt_all(const float* __restrict__ cw2, const float* __restrict__ cw3,
                        const float* __restrict__ cw4, const float* __restrict__ aw,
                        const float* __restrict__ wi0, const float* __restrict__ wi1,
                        u16* __restrict__ oh, u16* __restrict__ ol) {
  const int i = blockIdx.x * 256 + threadIdx.x;
  if (i >= CVT_N) return;
  float v;
  if (i < (int)W3_E) {
    const int l = i, oc = l / 288, rem = l - oc * 288, e = rem >> 5, ic = rem & 31;
    v = cw2[((size_t)(oc * 32 + ic) * 3 + e / 3) * 3 + e % 3];
  } else if (i < (int)W4_E) {
    const int l = i - (int)W3_E, oc = l / 576, rem = l - oc * 576, e = rem >> 6, ic = rem & 63;
    v = cw3[((size_t)(oc * 64 + ic) * 3 + e / 3) * 3 + e % 3];
  } else if (i < (int)AW_E) {
    const int l = i - (int)W4_E, oc = l / 1152, rem = l - oc * 1152, e = rem >> 7, ic = rem & 127;
    v = cw4[((size_t)(oc * 128 + ic) * 3 + e / 3) * 3 + e % 3];
  } else if (i < (int)WI0_E) {
    v = aw[i - (int)AW_E];
  } else if (i < (int)WI1_E) {
    v = wi0[i - (int)WI0_E];
  } else {
    v = wi1[i - (int)WI1_E];
  }
  const u16 h = f2b(v);
  oh[i] = h;
  ol[i] = f2b(v - b2f(h));
}

// ---------------- fused conv1(s2)+BN+ReLU+pool2 -> bf16 hi/lo NHWC ----------
__global__ __launch_bounds__(256) void conv1_pool(
    const float* __restrict__ support, const float* __restrict__ query,
    const float* __restrict__ w1, const float* __restrict__ cb1,
    const float* __restrict__ g1, const float* __restrict__ be1,
    u16* __restrict__ outh, u16* __restrict__ outl) {
  __shared__ float wl[288], scl[32], shl[32], cbl[32];
  const int tid = threadIdx.x;
  for (int l = tid; l < 288; l += 256) wl[l] = w1[l];
  if (tid < 32) { scl[tid] = g1[tid] * BN_INV; shl[tid] = be1[tid]; cbl[tid] = cb1[tid]; }
  __syncthreads();
  const int oc = tid & 31;
  const int p = blockIdx.x * 8 + (tid >> 5);
  const int ox = p % 56, oy = (p / 56) % 56, b = p / 3136;
  const float* in_b = (b < NS) ? (support + (size_t)b * 50176)
                               : (query + (size_t)(b - NS) * 50176);
  const int iy0 = 4 * oy - 1, ix0 = 4 * ox - 1;
  float pat[5][5];
#pragma unroll
  for (int dy = 0; dy < 5; ++dy) {
    const int iy = iy0 + dy;
#pragma unroll
    for (int dx = 0; dx < 5; ++dx) {
      const int ix = ix0 + dx;
      pat[dy][dx] = (iy >= 0 && iy < 224 && ix >= 0 && ix < 224)
                        ? in_b[(size_t)iy * 224 + ix] : 0.f;
    }
  }
  const float* wp = &wl[oc * 9];
  float mx = 0.f;
#pragma unroll
  for (int py = 0; py < 2; ++py)
#pragma unroll
    for (int px = 0; px < 2; ++px) {
      float acc = 0.f;
#pragma unroll
      for (int ky = 0; ky < 3; ++ky)
#pragma unroll
        for (int kx = 0; kx < 3; ++kx)
          acc += pat[2 * py + ky][2 * px + kx] * wp[ky * 3 + kx];
      float v = (acc + cbl[oc]) * scl[oc] + shl[oc];
      mx = fmaxf(mx, v);
    }
  const u16 h = f2b(mx);
  outh[(size_t)p * 32 + oc] = h;
  outl[(size_t)p * 32 + oc] = f2b(mx - b2f(h));
}

// ---------------- f32 NHWC maxpool 2x2 -> bf16 hi/lo planes -----------------
__global__ void maxpool2_split(const float* __restrict__ X, u16* __restrict__ Yh,
                               u16* __restrict__ Yl, int Bn, int H, int W, int C) {
  const int OH = H >> 1, OW = W >> 1;
  const int cpr = C >> 2;
  const int chunks = Bn * OH * OW * cpr;
  for (int i = blockIdx.x * blockDim.x + threadIdx.x; i < chunks;
       i += gridDim.x * blockDim.x) {
    const int c4 = i % cpr, m = i / cpr;
    const int ox = m % OW, oy = (m / OW) % OH, b = m / (OW * OH);
    const size_t base = (((size_t)b * H + 2 * oy) * W + 2 * ox) * C + (c4 << 2);
    const float4 r0 = *(const float4*)&X[base];
    const float4 r1 = *(const float4*)&X[base + C];
    const float4 r2 = *(const float4*)&X[base + (size_t)W * C];
    const float4 r3 = *(const float4*)&X[base + (size_t)W * C + C];
    float o[4];
    o[0] = fmaxf(fmaxf(r0.x, r1.x), fmaxf(r2.x, r3.x));
    o[1] = fmaxf(fmaxf(r0.y, r1.y), fmaxf(r2.y, r3.y));
    o[2] = fmaxf(fmaxf(r0.z, r1.z), fmaxf(r2.z, r3.z));
    o[3] = fmaxf(fmaxf(r0.w, r1.w), fmaxf(r2.w, r3.w));
    u16 hh[4], ll[4];
#pragma unroll
    for (int j = 0; j < 4; ++j) {
      hh[j] = f2b(o[j]);
      ll[j] = f2b(o[j] - b2f(hh[j]));
    }
    const size_t off = (size_t)m * C + (c4 << 2);
    uint2 vh, vl;
    vh.x = (u32)hh[0] | ((u32)hh[1] << 16); vh.y = (u32)hh[2] | ((u32)hh[3] << 16);
    vl.x = (u32)ll[0] | ((u32)ll[1] << 16); vl.y = (u32)ll[2] | ((u32)ll[3] << 16);
    *(uint2*)&Yh[off] = vh;
    *(uint2*)&Yl[off] = vl;
  }
}

// ---------------- 64x64-tile split-bf16 MFMA GEMM (proven; N=64 users) ------
template <int AMODE, int EPI>
__global__ __launch_bounds__(256) void sgemm(
    const u16* __restrict__ Ah, const u16* __restrict__ Al,
    const u16* __restrict__ A2h, const u16* __restrict__ A2l, int M, int K,
    const u16* __restrict__ Bh, const u16* __restrict__ Bl,
    const float* __restrict__ p0, const float* __restrict__ p1,
    const float* __restrict__ p2, float* __restrict__ Cout, int ldc,
    int H, int W, int IC, int icb) {
  __shared__ u16 Ash[64][72], Asl[64][72];
  __shared__ u16 Bsh[64][72], Bsl[64][72];
  const int tid = threadIdx.x;
  const int lane = tid & 63, wv = tid >> 6;
  const int wy = wv >> 1, wx = wv & 1;
  const int n0 = blockIdx.x * 64, m0 = blockIdx.y * 64;
  f32x4 acc[2][2] = {{{0, 0, 0, 0}, {0, 0, 0, 0}}, {{0, 0, 0, 0}, {0, 0, 0, 0}}};
  for (int k0 = 0; k0 < K; k0 += 64) {
#pragma unroll
    for (int s = 0; s < 2; ++s) {
      const int cc = s * 256 + tid;
      const int row = cc >> 3, kc = (cc & 7) << 3;
      const int gm = m0 + row, gk = k0 + kc;
      uint4 vh = {0u, 0u, 0u, 0u}, vl = {0u, 0u, 0u, 0u};
      if (AMODE == 0) {
        if (gm < M && gk < K) {
          const size_t idx = (size_t)gm * K + gk;
          vh = *(const uint4*)&Ah[idx];
          vl = *(const uint4*)&Al[idx];
        }
      } else if (AMODE == 1) {
        if (gm < M) {
          size_t idx;
          const u16 *ph_, *pl_;
          if (gk < 256) {
            idx = (size_t)gm * 256 + gk; ph_ = Ah; pl_ = Al;
          } else {
            const int b = gm / T49, t = gm % T49, q = b / NS;
            idx = (((size_t)(NS + q) * T49 + t) << 8) + (gk - 256);
            ph_ = A2h; pl_ = A2l;
          }
          vh = *(const uint4*)&ph_[idx];
          vl = *(const uint4*)&pl_[idx];
        }
      } else {
        if (gm < M && gk < K) {
          const int ox = gm % W, t_ = gm / W;
          const int oy = t_ % H, b = t_ / H;
          const int e = gk >> icb, ic = gk & (IC - 1);
          const int ky = e / 3, kx = e - 3 * (e / 3);
          const int iy = oy + ky - 1, ix = ox + kx - 1;
          if (iy >= 0 && iy < H && ix >= 0 && ix < W) {
            const size_t idx = (((size_t)b * H + iy) * W + ix) * IC + ic;
            vh = *(const uint4*)&Ah[idx];
            vl = *(const uint4*)&Al[idx];
          }
        }
      }
      *(uint4*)&Ash[row][kc] = vh;
      *(uint4*)&Asl[row][kc] = vl;
    }
#pragma unroll
    for (int s = 0; s < 2; ++s) {
      const int cc = s * 256 + tid;
      const int row = cc >> 3, kc = (cc & 7) << 3;
      const int gk = k0 + kc;
      uint4 vh = {0u, 0u, 0u, 0u}, vl = {0u, 0u, 0u, 0u};
      if (gk < K) {
        vh = *(const uint4*)&Bh[(size_t)(n0 + row) * K + gk];
        vl = *(const uint4*)&Bl[(size_t)(n0 + row) * K + gk];
      }
      *(uint4*)&Bsh[row][kc] = vh;
      *(uint4*)&Bsl[row][kc] = vl;
    }
    __syncthreads();
#pragma unroll
    for (int kk = 0; kk < 64; kk += 32) {
      const int ko = kk + ((lane >> 4) << 3);
      const int ra0 = wy * 32 + (lane & 15), ra1 = ra0 + 16;
      const int rb0 = wx * 32 + (lane & 15), rb1 = rb0 + 16;
      bf16x8v a0h = *(const bf16x8v*)&Ash[ra0][ko];
      bf16x8v a1h = *(const bf16x8v*)&Ash[ra1][ko];
      bf16x8v b0h = *(const bf16x8v*)&Bsh[rb0][ko];
      bf16x8v b1h = *(const bf16x8v*)&Bsh[rb1][ko];
      bf16x8v a0l = *(const bf16x8v*)&Asl[ra0][ko];
      bf16x8v a1l = *(const bf16x8v*)&Asl[ra1][ko];
      bf16x8v b0l = *(const bf16x8v*)&Bsl[rb0][ko];
      bf16x8v b1l = *(const bf16x8v*)&Bsl[rb1][ko];
      acc[0][0] = __builtin_amdgcn_mfma_f32_16x16x32_bf16(a0h, b0h, acc[0][0], 0, 0, 0);
      acc[0][1] = __builtin_amdgcn_mfma_f32_16x16x32_bf16(a0h, b1h, acc[0][1], 0, 0, 0);
      acc[1][0] = __builtin_amdgcn_mfma_f32_16x16x32_bf16(a1h, b0h, acc[1][0], 0, 0, 0);
      acc[1][1] = __builtin_amdgcn_mfma_f32_16x16x32_bf16(a1h, b1h, acc[1][1], 0, 0, 0);
      acc[0][0] = __builtin_amdgcn_mfma_f32_16x16x32_bf16(a0h, b0l, acc[0][0], 0, 0, 0);
      acc[0][1] = __builtin_amdgcn_mfma_f32_16x16x32_bf16(a0h, b1l, acc[0][1], 0, 0, 0);
      acc[1][0] = __builtin_amdgcn_mfma_f32_16x16x32_bf16(a1h, b0l, acc[1][0], 0, 0, 0);
      acc[1][1] = __builtin_amdgcn_mfma_f32_16x16x32_bf16(a1h, b1l, acc[1][1], 0, 0, 0);
      acc[0][0] = __builtin_amdgcn_mfma_f32_16x16x32_bf16(a0l, b0h, acc[0][0], 0, 0, 0);
      acc[0][1] = __builtin_amdgcn_mfma_f32_16x16x32_bf16(a0l, b1h, acc[0][1], 0, 0, 0);
      acc[1][0] = __builtin_amdgcn_mfma_f32_16x16x32_bf16(a1l, b0h, acc[1][0], 0, 0, 0);
      acc[1][1] = __builtin_amdgcn_mfma_f32_16x16x32_bf16(a1l, b1h, acc[1][1], 0, 0, 0);
    }
    __syncthreads();
  }
#pragma unroll
  for (int r = 0; r < 2; ++r) {
#pragma unroll
    for (int cI = 0; cI < 2; ++cI) {
      const int gn = n0 + wx * 32 + cI * 16 + (lane & 15);
      float sc0 = 0.f, sh0 = 0.f;
      if (EPI == 0) { sc0 = p1[gn] * BN_INV; sh0 = p2[gn]; }
#pragma unroll
      for (int i = 0; i < 4; ++i) {
        const int gm = m0 + wy * 32 + r * 16 + ((lane >> 4) << 2) + i;
        if (gm >= M) continue;
        const float a = acc[r][cI][i];
        if (EPI == 0) {
          Cout[(size_t)gm * ldc + gn] = fmaxf((a + p0[gn]) * sc0 + sh0, 0.f);
        } else {
          Cout[(size_t)gm * ldc + gn] = a + p0[gn];
        }
      }
    }
  }
}

// ---------------- 128x128-tile split-bf16 MFMA GEMM (r20) -------------------
// m93 ladder shape: 256 thr / 4 waves, wave-tile 64x64 = 4x4 16x16 fragments.
// Same fragment offsets and C/D mapping as the validated 64-tile kernel
// (generalized 2x2 -> 4x4). MFMA:ds_read ratio 1.5 -> 3.0. LDS 73.7 KB.
template <int AMODE, int EPI>
__global__ __launch_bounds__(256) void sgemm128(
    const u16* __restrict__ Ah, const u16* __restrict__ Al,
    const u16* __restrict__ A2h, const u16* __restrict__ A2l, int M, int K,
    const u16* __restrict__ Bh, const u16* __restrict__ Bl,
    const float* __restrict__ p0, const float* __restrict__ p1,
    const float* __restrict__ p2, float* __restrict__ Cout, int ldc,
    int H, int W, int IC, int icb) {
  __shared__ u16 Ash[128][72], Asl[128][72];
  __shared__ u16 Bsh[128][72], Bsl[128][72];
  const int tid = threadIdx.x;
  const int lane = tid & 63, wv = tid >> 6;
  const int wy = wv >> 1, wx = wv & 1;   // 2x2 waves, each 64x64
  const int n0 = blockIdx.x * 128, m0 = blockIdx.y * 128;
  f32x4 acc[4][4];
#pragma unroll
  for (int r = 0; r < 4; ++r)
#pragma unroll
    for (int c = 0; c < 4; ++c) acc[r][c] = (f32x4){0, 0, 0, 0};
  for (int k0 = 0; k0 < K; k0 += 64) {
    // ---- stage A: 128 rows x 64 cols, 1024 16B-chunks over 256 thr ----
#pragma unroll
    for (int s = 0; s < 4; ++s) {
      const int cc = s * 256 + tid;
      const int row = cc >> 3, kc = (cc & 7) << 3;
      const int gm = m0 + row, gk = k0 + kc;
      uint4 vh = {0u, 0u, 0u, 0u}, vl = {0u, 0u, 0u, 0u};
      if (AMODE == 0) {
        if (gm < M && gk < K) {
          const size_t idx = (size_t)gm * K + gk;
          vh = *(const uint4*)&Ah[idx];
          vl = *(const uint4*)&Al[idx];
        }
      } else if (AMODE == 1) {
        if (gm < M) {
          size_t idx;
          const u16 *ph_, *pl_;
          if (gk < 256) {
            idx = (size_t)gm * 256 + gk; ph_ = Ah; pl_ = Al;
          } else {
            const int b = gm / T49, t = gm % T49, q = b / NS;
            idx = (((size_t)(NS + q) * T49 + t) << 8) + (gk - 256);
            ph_ = A2h; pl_ = A2l;
          }
          vh = *(const uint4*)&ph_[idx];
          vl = *(const uint4*)&pl_[idx];
        }
      } else {  // implicit im2col
        if (gm < M && gk < K) {
          const int ox = gm % W, t_ = gm / W;
          const int oy = t_ % H, b = t_ / H;
          const int e = gk >> icb, ic = gk & (IC - 1);
          const int ky = e / 3, kx = e - 3 * (e / 3);
          const int iy = oy + ky - 1, ix = ox + kx - 1;
          if (iy >= 0 && iy < H && ix >= 0 && ix < W) {
            const size_t idx = (((size_t)b * H + iy) * W + ix) * IC + ic;
            vh = *(const uint4*)&Ah[idx];
            vl = *(const uint4*)&Al[idx];
          }
        }
      }
      *(uint4*)&Ash[row][kc] = vh;
      *(uint4*)&Asl[row][kc] = vl;
    }
    // ---- stage B: 128 rows x 64 cols ----
#pragma unroll
    for (int s = 0; s < 4; ++s) {
      const int cc = s * 256 + tid;
      const int row = cc >> 3, kc = (cc & 7) << 3;
      const int gk = k0 + kc;
      uint4 vh = {0u, 0u, 0u, 0u}, vl = {0u, 0u, 0u, 0u};
      if (gk < K) {
        vh = *(const uint4*)&Bh[(size_t)(n0 + row) * K + gk];
        vl = *(const uint4*)&Bl[(size_t)(n0 + row) * K + gk];
      }
      *(uint4*)&Bsh[row][kc] = vh;
      *(uint4*)&Bsl[row][kc] = vl;
    }
    __syncthreads();
#pragma unroll
    for (int kk = 0; kk < 64; kk += 32) {
      const int ko = kk + ((lane >> 4) << 3);
      bf16x8v ah[4], al[4], bh[4], bl[4];
#pragma unroll
      for (int r = 0; r < 4; ++r) {
        const int ra = wy * 64 + r * 16 + (lane & 15);
        ah[r] = *(const bf16x8v*)&Ash[ra][ko];
        al[r] = *(const bf16x8v*)&Asl[ra][ko];
      }
#pragma unroll
      for (int c = 0; c < 4; ++c) {
        const int rb = wx * 64 + c * 16 + (lane & 15);
        bh[c] = *(const bf16x8v*)&Bsh[rb][ko];
        bl[c] = *(const bf16x8v*)&Bsl[rb][ko];
      }
#pragma unroll
      for (int r = 0; r < 4; ++r)
#pragma unroll
        for (int c = 0; c < 4; ++c)
          acc[r][c] = __builtin_amdgcn_mfma_f32_16x16x32_bf16(ah[r], bh[c], acc[r][c], 0, 0, 0);
#pragma unroll
      for (int r = 0; r < 4; ++r)
#pragma unroll
        for (int c = 0; c < 4; ++c)
          acc[r][c] = __builtin_amdgcn_mfma_f32_16x16x32_bf16(ah[r], bl[c], acc[r][c], 0, 0, 0);
#pragma unroll
      for (int r = 0; r < 4; ++r)
#pragma unroll
        for (int c = 0; c < 4; ++c)
          acc[r][c] = __builtin_amdgcn_mfma_f32_16x16x32_bf16(al[r], bh[c], acc[r][c], 0, 0, 0);
    }
    __syncthreads();
  }
  // ---- epilogue ----
#pragma unroll
  for (int r = 0; r < 4; ++r) {
#pragma unroll
    for (int cI = 0; cI < 4; ++cI) {
      const int gn = n0 + wx * 64 + cI * 16 + (lane & 15);
      float sc0 = 0.f, sh0 = 0.f;
      if (EPI == 0) { sc0 = p1[gn] * BN_INV; sh0 = p2[gn]; }
#pragma unroll
      for (int i = 0; i < 4; ++i) {
        const int gm = m0 + wy * 64 + r * 16 + ((lane >> 4) << 2) + i;
        if (gm >= M) continue;
        const float a = acc[r][cI][i];
        if (EPI == 0) {
          Cout[(size_t)gm * ldc + gn] = fmaxf((a + p0[gn]) * sc0 + sh0, 0.f);
        } else {
          Cout[(size_t)gm * ldc + gn] = a + p0[gn];
        }
      }
    }
  }
}

// ---------------- fused attention, block = (q,s,t-group of 7) ---------------
__global__ __launch_bounds__(256) void attention_f32(
    const float* __restrict__ proj, const u16* __restrict__ featTh,
    const u16* __restrict__ featTl, u16* __restrict__ atth,
    u16* __restrict__ attl) {
  __shared__ float WqT[64][9];
  __shared__ float WhT[64][51];
  __shared__ float sc[7][64];
  const int bid = blockIdx.x;
  const int qs = bid / 7, tg = bid - 7 * qs;
  const int q = qs / NS, s = qs - NS * q;
  const int tid = threadIdx.x;
  const float* pq = proj + ((size_t)(NS + q) * T49 + tg * 7) * 64;
  const float* ph = proj + (size_t)s * T49 * 64;
  for (int l = tid; l < 7 * 64; l += 256) WqT[l & 63][l >> 6] = pq[l];
  for (int l = tid; l < T49 * 64; l += 256) WhT[l & 63][l >> 6] = ph[l];
  __syncthreads();
  constexpr float C2LOG2E = 2.8853900817779268f;
  for (int e = tid; e < 343; e += 256) {
    const int tl = e / 49, u = e - 49 * tl;
    float a0 = 0.f, a1 = 0.f, a2 = 0.f, a3 = 0.f;
#pragma unroll
    for (int h = 0; h < 64; h += 4) {
      const float p0 = WqT[h + 0][tl] * WhT[h + 0][u];
      const float p1 = WqT[h + 1][tl] * WhT[h + 1][u];
      const float p2 = WqT[h + 2][tl] * WhT[h + 2][u];
      const float p3 = WqT[h + 3][tl] * WhT[h + 3][u];
      a0 += 1.f - 2.f * __builtin_amdgcn_rcpf(__builtin_amdgcn_exp2f(p0 * C2LOG2E) + 1.f);
      a1 += 1.f - 2.f * __builtin_amdgcn_rcpf(__builtin_amdgcn_exp2f(p1 * C2LOG2E) + 1.f);
      a2 += 1.f - 2.f * __builtin_amdgcn_rcpf(__builtin_amdgcn_exp2f(p2 * C2LOG2E) + 1.f);
      a3 += 1.f - 2.f * __builtin_amdgcn_rcpf(__builtin_amdgcn_exp2f(p3 * C2LOG2E) + 1.f);
    }
    sc[tl][u] = (a0 + a1) + (a2 + a3);
  }
  __syncthreads();
  if (tid < 56) {
    const int t = tid >> 3, g = tid & 7;
    float m = -3.4e38f;
    for (int u = g; u < T49; u += 8) m = fmaxf(m, sc[t][u]);
    m = fmaxf(m, __shfl_xor(m, 4));
    m = fmaxf(m, __shfl_xor(m, 2));
    m = fmaxf(m, __shfl_xor(m, 1));
    float ssum = 0.f;
    for (int u = g; u < T49; u += 8) {
      const float e = __builtin_amdgcn_exp2f((sc[t][u] - m) * LOG2E);
      sc[t][u] = e; ssum += e;
    }
    ssum += __shfl_xor(ssum, 4);
    ssum += __shfl_xor(ssum, 2);
    ssum += __shfl_xor(ssum, 1);
    const float inv = 1.f / ssum;
    for (int u = g; u < T49; u += 8) sc[t][u] *= inv;
  }
  __syncthreads();
  const u16* fsh = featTh + (size_t)s * T49 * 256;
  const u16* fsl = featTl + (size_t)s * T49 * 256;
  const size_t obase = ((size_t)qs * T49 + tg * 7) * 256;
  float acc[7] = {0.f, 0.f, 0.f, 0.f, 0.f, 0.f, 0.f};
  for (int u = 0; u < T49; ++u) {
    const float v = b2f(fsh[u * 256 + tid]) + b2f(fsl[u * 256 + tid]);
#pragma unroll
    for (int i = 0; i < 7; ++i) acc[i] += sc[i][u] * v;
  }
#pragma unroll
  for (int i = 0; i < 7; ++i) {
    const float a = acc[i];
    const u16 h = f2b(a);
    atth[obase + (size_t)i * 256 + tid] = h;
    attl[obase + (size_t)i * 256 + tid] = f2b(a - b2f(h));
  }
}

// ---------------- batched MFMA GRU (r16 structure, 53.5us measured) ---------
constexpr int SPB = 8;
__global__ __launch_bounds__(512) void gru_mfma(
    const float* __restrict__ gi,
    const float* __restrict__ wh,
    const float* __restrict__ bh,
    u16* __restrict__ yh, u16* __restrict__ yl,
    float* __restrict__ hfin,
    int store_all) {
  __shared__ u16 hah[16][136];
  __shared__ float ghs[SPB][384];
  __shared__ float hfl[SPB][128];
  const int tid = threadIdx.x;
  const int lane = tid & 63, wv = tid >> 6;
  const int r0 = blockIdx.x * SPB;
  bf16x8v Bhr[3][4], Blr[3][4];
#pragma unroll
  for (int f = 0; f < 3; ++f) {
    const int n = (wv * 3 + f) * 16 + (lane & 15);
#pragma unroll
    for (int kk = 0; kk < 4; ++kk) {
      const int k = kk * 32 + ((lane >> 4) << 3);
      const float* p = wh + (size_t)n * 128 + k;
      float v[8];
      *(float4*)&v[0] = *(const float4*)p;
      *(float4*)&v[4] = *(const float4*)(p + 4);
      u32 hp[4], lp[4];
      split8(v, hp, lp);
      Bhr[f][kk] = *(bf16x8v*)hp;
      Blr[f][kk] = *(bf16x8v*)lp;
    }
  }
  const int row0 = tid >> 7, j0 = tid & 127;
  const int row1 = (512 + tid) >> 7, j1 = tid & 127;
  int sq0 = r0 + row0; if (sq0 >= B3) sq0 = B3 - 1;
  int sq1 = r0 + row1; if (sq1 >= B3) sq1 = B3 - 1;
  const float bhr0 = bh[j0], bhz0 = bh[128 + j0], bhn0 = bh[256 + j0];
  const float bhr1 = bh[j1], bhz1 = bh[128 + j1], bhn1 = bh[256 + j1];
  const float* gib0 = gi + (size_t)sq0 * T49 * 384;
  const float* gib1 = gi + (size_t)sq1 * T49 * 384;
  for (int i = tid; i < 16 * 136; i += 512) hah[i / 136][i % 136] = 0;
  for (int i = tid; i < SPB * 128; i += 512) hfl[i >> 7][i & 127] = 0.f;
  __syncthreads();
  const int ar = lane & 15, ko = (lane >> 4) << 3;
  float xr0c = gib0[j0], xz0c = gib0[128 + j0], xn0c = gib0[256 + j0];
  float xr1c = gib1[j1], xz1c = gib1[128 + j1], xn1c = gib1[256 + j1];
  for (int t = 0; t < T49; ++t) {
    const int tn = (t + 1 < T49) ? t + 1 : t;
    const float* g0n = gib0 + (size_t)tn * 384;
    const float* g1n = gib1 + (size_t)tn * 384;
    const float xr0n = g0n[j0], xz0n = g0n[128 + j0], xn0n = g0n[256 + j0];
    const float xr1n = g1n[j1], xz1n = g1n[128 + j1], xn1n = g1n[256 + j1];
    bf16x8v Ah[4];
#pragma unroll
    for (int kk = 0; kk < 4; ++kk)
      Ah[kk] = *(const bf16x8v*)&hah[ar][kk * 32 + ko];
#pragma unroll
    for (int f = 0; f < 3; ++f) {
      f32x4 acc = {0, 0, 0, 0};
#pragma unroll
      for (int kk = 0; kk < 4; ++kk)
        acc = __builtin_amdgcn_mfma_f32_16x16x32_bf16(Ah[kk], Bhr[f][kk], acc, 0, 0, 0);
#pragma unroll
      for (int kk = 0; kk < 4; ++kk)
        acc = __builtin_amdgcn_mfma_f32_16x16x32_bf16(Ah[kk], Blr[f][kk], acc, 0, 0, 0);
      const int nc = (wv * 3 + f) * 16 + (lane & 15);
      const int rb = (lane >> 4) << 2;
      if (rb < SPB) {
#pragma unroll
        for (int i = 0; i < 4; ++i) ghs[rb + i][nc] = acc[i];
      }
    }
    __syncthreads();
    {
      const float r_ = fsigmoid(xr0c + ghs[row0][j0] + bhr0);
      const float z_ = fsigmoid(xz0c + ghs[row0][128 + j0] + bhz0);
      const float n_ = ftanh(xn0c + r_ * (ghs[row0][256 + j0] + bhn0));
      const float hn = (1.f - z_) * n_ + z_ * hfl[row0][j0];
      hfl[row0][j0] = hn;
      const u16 hb = f2b(hn);
      hah[row0][j0] = hb;
      if (r0 + row0 < B3) {
        if (store_all) {
          const size_t o = ((size_t)(r0 + row0) * T49 + t) * 128 + j0;
          yh[o] = hb;
          yl[o] = f2b(hn - b2f(hb));
        } else if (t == T49 - 1) {
          hfin[(size_t)(r0 + row0) * 128 + j0] = hn;
        }
      }
    }
    {
      const float r_ = fsigmoid(xr1c + ghs[row1][j1] + bhr1);
      const float z_ = fsigmoid(xz1c + ghs[row1][128 + j1] + bhz1);
      const float n_ = ftanh(xn1c + r_ * (ghs[row1][256 + j1] + bhn1));
      const float hn = (1.f - z_) * n_ + z_ * hfl[row1][j1];
      hfl[row1][j1] = hn;
      const u16 hb = f2b(hn);
      hah[row1][j1] = hb;
      if (r0 + row1 < B3) {
        if (store_all) {
          const size_t o = ((size_t)(r0 + row1) * T49 + t) * 128 + j1;
          yh[o] = hb;
          yl[o] = f2b(hn - b2f(hb));
        } else if (t == T49 - 1) {
          hfin[(size_t)(r0 + row1) * 128 + j1] = hn;
        }
      }
    }
    __syncthreads();
    xr0c = xr0n; xz0c = xz0n; xn0c = xn0n;
    xr1c = xr1n; xz1c = xz1n; xn1c = xn1n;
  }
}

// ---------------- head ----------------
__global__ __launch_bounds__(512) void head_kernel(
    const float* __restrict__ hf, const float* __restrict__ tw,
    const float* __restrict__ tb, float* __restrict__ out) {
  __shared__ float lg[B3];
  const int tid = threadIdx.x;
  if (tid < B3) {
    const float* h = hf + (size_t)tid * 128;
    float acc = tb[0];
    for (int k = 0; k < 128; ++k) acc += h[k] * tw[k];
    lg[tid] = acc;
  }
  __syncthreads();
  if (tid < NQ) {
    float cls[5];
#pragma unroll
    for (int n = 0; n < 5; ++n) {
      float s = 0.f;
#pragma unroll
      for (int k = 0; k < 5; ++k) s += lg[tid * 25 + n * 5 + k];
      cls[n] = s;
    }
    float m = cls[0];
#pragma unroll
    for (int n = 1; n < 5; ++n) m = fmaxf(m, cls[n]);
    float se = 0.f;
#pragma unroll
    for (int n = 0; n < 5; ++n) se += expf(cls[n] - m);
    const float lse = m + logf(se);
#pragma unroll
    for (int n = 0; n < 5; ++n) out[tid * 5 + n] = cls[n] - lse;
  }
}

extern "C" void kernel_launch(void* const* d_in, const int* in_sizes, int n_in,
                              void* d_out, int out_size, void* d_ws,
                              size_t ws_size, hipStream_t stream) {
  (void)in_sizes; (void)n_in; (void)out_size; (void)ws_size;
  const float* support = (const float*)d_in[0];
  const float* query   = (const float*)d_in[1];
  const float* cw1 = (const float*)d_in[2];  const float* cb1 = (const float*)d_in[3];
  const float* cw2 = (const float*)d_in[4];  const float* cb2 = (const float*)d_in[5];
  const float* cw3 = (const float*)d_in[6];  const float* cb3 = (const float*)d_in[7];
  const float* cw4 = (const float*)d_in[8];  const float* cb4 = (const float*)d_in[9];
  const float* g1  = (const float*)d_in[10]; const float* be1 = (const float*)d_in[11];
  const float* g2  = (const float*)d_in[12]; const float* be2 = (const float*)d_in[13];
  const float* g3  = (const float*)d_in[14]; const float* be3 = (const float*)d_in[15];
  const float* g4  = (const float*)d_in[16]; const float* be4 = (const float*)d_in[17];
  const float* aw  = (const float*)d_in[18]; const float* ab  = (const float*)d_in[19];
  const float* wi0 = (const float*)d_in[20]; const float* wh0 = (const float*)d_in[21];
  const float* bi0 = (const float*)d_in[22]; const float* bh0 = (const float*)d_in[23];
  const float* wi1 = (const float*)d_in[24]; const float* wh1 = (const float*)d_in[25];
  const float* bi1 = (const float*)d_in[26]; const float* bh1 = (const float*)d_in[27];
  const float* tw  = (const float*)d_in[28]; const float* tb  = (const float*)d_in[29];

  char* ws = (char*)d_ws;
  float* out = (float*)d_out;
  u16* A1H    = (u16*)(ws + A1H_OFF);
  u16* A1L    = (u16*)(ws + A1L_OFF);
  float* X2   = (float*)(ws + X2_OFF);
  u16* P2H    = (u16*)(ws + P2H_OFF);
  u16* P2L    = (u16*)(ws + P2L_OFF);
  float* X3   = (float*)(ws + X3_OFF);
  u16* P3H    = (u16*)(ws + P3H_OFF);
  u16* P3L    = (u16*)(ws + P3L_OFF);
  float* X4   = (float*)(ws + X4_OFF);
  u16* FEATTH = (u16*)(ws + FEATTH_OFF);
  u16* FEATTL = (u16*)(ws + FEATTL_OFF);
  float* PROJ = (float*)(ws + PROJ_OFF);
  u16* ATTH   = (u16*)(ws + ATTH_OFF);
  u16* ATTL   = (u16*)(ws + ATTL_OFF);
  float* GI   = (float*)(ws + GI_OFF);
  u16* Y0H    = (u16*)(ws + Y0H_OFF);
  u16* Y0L    = (u16*)(ws + Y0L_OFF);
  float* HFIN = (float*)(ws + HFIN_OFF);
  u16* WBH = (u16*)(ws + WBH_OFF);
  u16* WBL = (u16*)(ws + WBL_OFF);

  // weight conversions (single fused launch)
  cvt_all<<<(CVT_N + 255) / 256, 256, 0, stream>>>(cw2, cw3, cw4, aw, wi0, wi1, WBH, WBL);

  // ---- encoder ----
  conv1_pool<<<15680, 256, 0, stream>>>(support, query, cw1, cb1, g1, be1, A1H, A1L);
  // conv2 (N=64): 64-tile
  sgemm<2, 0><<<dim3(1, 1960), 256, 0, stream>>>(
      A1H, A1L, nullptr, nullptr, 125440, 288, WBH + W2_E, WBL + W2_E,
      cb2, g2, be2, X2, 64, 56, 56, 32, 5);
  maxpool2_split<<<1960, 256, 0, stream>>>(X2, P2H, P2L, NB, 56, 56, 64);
  // conv3 (N=128): 128-tile
  sgemm128<2, 0><<<dim3(1, 245), 256, 0, stream>>>(
      P2H, P2L, nullptr, nullptr, 31360, 576, WBH + W3_E, WBL + W3_E,
      cb3, g3, be3, X3, 128, 28, 28, 64, 6);
  maxpool2_split<<<980, 256, 0, stream>>>(X3, P3H, P3L, NB, 28, 28, 128);
  // conv4 (N=256): 128-tile
  sgemm128<2, 0><<<dim3(2, 62), 256, 0, stream>>>(
      P3H, P3L, nullptr, nullptr, 7840, 1152, WBH + W4_E, WBL + W4_E,
      cb4, g4, be4, X4, 256, 14, 14, 128, 7);
  maxpool2_split<<<490, 256, 0, stream>>>(X4, FEATTH, FEATTL, NB, 14, 14, 256);

  // ---- attention ----
  sgemm<0, 1><<<dim3(1, 31), 256, 0, stream>>>(
      FEATTH, FEATTL, nullptr, nullptr, NB * T49, 256, WBH + AW_E, WBL + AW_E,
      ab, nullptr, nullptr, PROJ, 64, 0, 0, 0, 0);
  attention_f32<<<B3 * 7, 256, 0, stream>>>(PROJ, FEATTH, FEATTL, ATTH, ATTL);

  // ---- GRU stack ----
  sgemm128<1, 1><<<dim3(3, 144), 256, 0, stream>>>(
      ATTH, ATTL, FEATTH, FEATTL, B3 * T49, 512, WBH + WI0_E, WBL + WI0_E,
      bi0, nullptr, nullptr, GI, 384, 0, 0, 0, 0);
  gru_mfma<<<47, 512, 0, stream>>>(GI, wh0, bh0, Y0H, Y0L, nullptr, 1);
  sgemm128<0, 1><<<dim3(3, 144), 256, 0, stream>>>(
      Y0H, Y0L, nullptr, nullptr, B3 * T49, 128, WBH + WI1_E, WBL + WI1_E,
      bi1, nullptr, nullptr, GI, 384, 0, 0, 0, 0);
  gru_mfma<<<47, 512, 0, stream>>>(GI, wh1, bh1, nullptr, nullptr, HFIN, 0);

  // ---- head ----
  head_kernel<<<1, 512, 0, stream>>>(HFIN, tw, tb, out);
}

// Round 21
// 368.566 us; speedup vs baseline: 1.1060x; 1.1060x over previous
//
#include <hip/hip_runtime.h>
#include <hip/hip_bf16.h>
#include <math.h>

typedef unsigned short u16;
typedef unsigned int u32;
typedef __attribute__((ext_vector_type(8))) short bf16x8v;
typedef __attribute__((ext_vector_type(4))) float f32x4;

// ---------------- problem constants ----------------
constexpr int NS = 25, NQ = 15, NB = 40;
constexpr int B3 = 375;     // 15*25
constexpr int T49 = 49;
constexpr float BN_INV = 0.9999950000374997f;

// ---------------- workspace layout (BYTES) ----------------------------------
constexpr size_t A1H_OFF    = 0;
constexpr size_t A1L_OFF    = 8028160;
constexpr size_t X2_OFF     = 16056320;
constexpr size_t P2H_OFF    = 48168960;
constexpr size_t P2L_OFF    = 52183040;
constexpr size_t X3_OFF     = 0;
constexpr size_t P3H_OFF    = 56197120;
constexpr size_t P3L_OFF    = 58204160;
constexpr size_t X4_OFF     = 0;
constexpr size_t FEATTH_OFF = 60211200;
constexpr size_t FEATTL_OFF = 61214720;
constexpr size_t PROJ_OFF   = 0;
constexpr size_t ATTH_OFF   = 16056320;
constexpr size_t ATTL_OFF   = 25464320;
constexpr size_t GI_OFF     = 62218240;
constexpr size_t Y0H_OFF    = 0;
constexpr size_t Y0L_OFF    = 4704000;
constexpr size_t HFIN_OFF   = 90442240;
constexpr size_t WBH_OFF    = 91027456;
constexpr size_t WBL_OFF    = 92325888;
constexpr size_t W2_E = 0;
constexpr size_t W3_E = 18432;
constexpr size_t W4_E = 92160;
constexpr size_t AW_E = 387072;
constexpr size_t WI0_E = 403456;
constexpr size_t WI1_E = 600064;
constexpr int CVT_N = 649216;

static __device__ __forceinline__ u16 f2b(float f) {
  __hip_bfloat16 h = __float2bfloat16(f);
  return *reinterpret_cast<u16*>(&h);
}
static __device__ __forceinline__ float b2f(u16 u) {
  return __uint_as_float((u32)u << 16);
}
constexpr float LOG2E = 1.4426950408889634f;
static __device__ __forceinline__ float fsigmoid(float x) {
  return __builtin_amdgcn_rcpf(1.f + __builtin_amdgcn_exp2f(-x * LOG2E));
}
static __device__ __forceinline__ float ftanh(float x) {
  return 1.f - 2.f * __builtin_amdgcn_rcpf(__builtin_amdgcn_exp2f(x * (2.f * LOG2E)) + 1.f);
}
static __device__ __forceinline__ void split8(const float* v, u32* hp, u32* lp) {
  u16 h[8], l[8];
#pragma unroll
  for (int j = 0; j < 8; ++j) {
    const u16 hb = f2b(v[j]);
    h[j] = hb;
    l[j] = f2b(v[j] - b2f(hb));
  }
#pragma unroll
  for (int j = 0; j < 4; ++j) {
    hp[j] = (u32)h[2 * j] | ((u32)h[2 * j + 1] << 16);
    lp[j] = (u32)l[2 * j] | ((u32)l[2 * j + 1] << 16);
  }
}

// ---------------- fused weight converter (1 launch) ----------------
__global__ void cvt_all(const float* __restrict__ cw2, const float* __restrict__ cw3,
                        const float* __restrict__ cw4, const float* __restrict__ aw,
                        const float* __restrict__ wi0, const float* __restrict__ wi1,
                        u16* __restrict__ oh, u16* __restrict__ ol) {
  const int i = blockIdx.x * 256 + threadIdx.x;
  if (i >= CVT_N) return;
  float v;
  if (i < (int)W3_E) {
    const int l = i, oc = l / 288, rem = l - oc * 288, e = rem >> 5, ic = rem & 31;
    v = cw2[((size_t)(oc * 32 + ic) * 3 + e / 3) * 3 + e % 3];
  } else if (i < (int)W4_E) {
    const int l = i - (int)W3_E, oc = l / 576, rem = l - oc * 576, e = rem >> 6, ic = rem & 63;
    v = cw3[((size_t)(oc * 64 + ic) * 3 + e / 3) * 3 + e % 3];
  } else if (i < (int)AW_E) {
    const int l = i - (int)W4_E, oc = l / 1152, rem = l - oc * 1152, e = rem >> 7, ic = rem & 127;
    v = cw4[((size_t)(oc * 128 + ic) * 3 + e / 3) * 3 + e % 3];
  } else if (i < (int)WI0_E) {
    v = aw[i - (int)AW_E];
  } else if (i < (int)WI1_E) {
    v = wi0[i - (int)WI0_E];
  } else {
    v = wi1[i - (int)WI1_E];
  }
  const u16 h = f2b(v);
  oh[i] = h;
  ol[i] = f2b(v - b2f(h));
}

// ---------------- fused conv1(s2)+BN+ReLU+pool2 -> bf16 hi/lo NHWC ----------
__global__ __launch_bounds__(256) void conv1_pool(
    const float* __restrict__ support, const float* __restrict__ query,
    const float* __restrict__ w1, const float* __restrict__ cb1,
    const float* __restrict__ g1, const float* __restrict__ be1,
    u16* __restrict__ outh, u16* __restrict__ outl) {
  __shared__ float wl[288], scl[32], shl[32], cbl[32];
  const int tid = threadIdx.x;
  for (int l = tid; l < 288; l += 256) wl[l] = w1[l];
  if (tid < 32) { scl[tid] = g1[tid] * BN_INV; shl[tid] = be1[tid]; cbl[tid] = cb1[tid]; }
  __syncthreads();
  const int oc = tid & 31;
  const int p = blockIdx.x * 8 + (tid >> 5);
  const int ox = p % 56, oy = (p / 56) % 56, b = p / 3136;
  const float* in_b = (b < NS) ? (support + (size_t)b * 50176)
                               : (query + (size_t)(b - NS) * 50176);
  const int iy0 = 4 * oy - 1, ix0 = 4 * ox - 1;
  float pat[5][5];
#pragma unroll
  for (int dy = 0; dy < 5; ++dy) {
    const int iy = iy0 + dy;
#pragma unroll
    for (int dx = 0; dx < 5; ++dx) {
      const int ix = ix0 + dx;
      pat[dy][dx] = (iy >= 0 && iy < 224 && ix >= 0 && ix < 224)
                        ? in_b[(size_t)iy * 224 + ix] : 0.f;
    }
  }
  const float* wp = &wl[oc * 9];
  float mx = 0.f;
#pragma unroll
  for (int py = 0; py < 2; ++py)
#pragma unroll
    for (int px = 0; px < 2; ++px) {
      float acc = 0.f;
#pragma unroll
      for (int ky = 0; ky < 3; ++ky)
#pragma unroll
        for (int kx = 0; kx < 3; ++kx)
          acc += pat[2 * py + ky][2 * px + kx] * wp[ky * 3 + kx];
      float v = (acc + cbl[oc]) * scl[oc] + shl[oc];
      mx = fmaxf(mx, v);
    }
  const u16 h = f2b(mx);
  outh[(size_t)p * 32 + oc] = h;
  outl[(size_t)p * 32 + oc] = f2b(mx - b2f(h));
}

// ---------------- f32 NHWC maxpool 2x2 -> bf16 hi/lo planes -----------------
__global__ void maxpool2_split(const float* __restrict__ X, u16* __restrict__ Yh,
                               u16* __restrict__ Yl, int Bn, int H, int W, int C) {
  const int OH = H >> 1, OW = W >> 1;
  const int cpr = C >> 2;
  const int chunks = Bn * OH * OW * cpr;
  for (int i = blockIdx.x * blockDim.x + threadIdx.x; i < chunks;
       i += gridDim.x * blockDim.x) {
    const int c4 = i % cpr, m = i / cpr;
    const int ox = m % OW, oy = (m / OW) % OH, b = m / (OW * OH);
    const size_t base = (((size_t)b * H + 2 * oy) * W + 2 * ox) * C + (c4 << 2);
    const float4 r0 = *(const float4*)&X[base];
    const float4 r1 = *(const float4*)&X[base + C];
    const float4 r2 = *(const float4*)&X[base + (size_t)W * C];
    const float4 r3 = *(const float4*)&X[base + (size_t)W * C + C];
    float o[4];
    o[0] = fmaxf(fmaxf(r0.x, r1.x), fmaxf(r2.x, r3.x));
    o[1] = fmaxf(fmaxf(r0.y, r1.y), fmaxf(r2.y, r3.y));
    o[2] = fmaxf(fmaxf(r0.z, r1.z), fmaxf(r2.z, r3.z));
    o[3] = fmaxf(fmaxf(r0.w, r1.w), fmaxf(r2.w, r3.w));
    u16 hh[4], ll[4];
#pragma unroll
    for (int j = 0; j < 4; ++j) {
      hh[j] = f2b(o[j]);
      ll[j] = f2b(o[j] - b2f(hh[j]));
    }
    const size_t off = (size_t)m * C + (c4 << 2);
    uint2 vh, vl;
    vh.x = (u32)hh[0] | ((u32)hh[1] << 16); vh.y = (u32)hh[2] | ((u32)hh[3] << 16);
    vl.x = (u32)ll[0] | ((u32)ll[1] << 16); vl.y = (u32)ll[2] | ((u32)ll[3] << 16);
    *(uint2*)&Yh[off] = vh;
    *(uint2*)&Yl[off] = vl;
  }
}

// ---------------- 64x64-tile split-bf16 MFMA GEMM (proven config) -----------
// r20 lesson: 128^2 tile starved occupancy at our small M/N (conv4: 124
// blocks -> 68.7us). 64^2 keeps >=492 blocks everywhere. Keep it.
template <int AMODE, int EPI>
__global__ __launch_bounds__(256) void sgemm(
    const u16* __restrict__ Ah, const u16* __restrict__ Al,
    const u16* __restrict__ A2h, const u16* __restrict__ A2l, int M, int K,
    const u16* __restrict__ Bh, const u16* __restrict__ Bl,
    const float* __restrict__ p0, const float* __restrict__ p1,
    const float* __restrict__ p2, float* __restrict__ Cout, int ldc,
    int H, int W, int IC, int icb) {
  __shared__ u16 Ash[64][72], Asl[64][72];
  __shared__ u16 Bsh[64][72], Bsl[64][72];
  const int tid = threadIdx.x;
  const int lane = tid & 63, wv = tid >> 6;
  const int wy = wv >> 1, wx = wv & 1;
  const int n0 = blockIdx.x * 64, m0 = blockIdx.y * 64;
  f32x4 acc[2][2] = {{{0, 0, 0, 0}, {0, 0, 0, 0}}, {{0, 0, 0, 0}, {0, 0, 0, 0}}};
  for (int k0 = 0; k0 < K; k0 += 64) {
#pragma unroll
    for (int s = 0; s < 2; ++s) {
      const int cc = s * 256 + tid;
      const int row = cc >> 3, kc = (cc & 7) << 3;
      const int gm = m0 + row, gk = k0 + kc;
      uint4 vh = {0u, 0u, 0u, 0u}, vl = {0u, 0u, 0u, 0u};
      if (AMODE == 0) {
        if (gm < M && gk < K) {
          const size_t idx = (size_t)gm * K + gk;
          vh = *(const uint4*)&Ah[idx];
          vl = *(const uint4*)&Al[idx];
        }
      } else if (AMODE == 1) {
        if (gm < M) {
          size_t idx;
          const u16 *ph_, *pl_;
          if (gk < 256) {
            idx = (size_t)gm * 256 + gk; ph_ = Ah; pl_ = Al;
          } else {
            const int b = gm / T49, t = gm % T49, q = b / NS;
            idx = (((size_t)(NS + q) * T49 + t) << 8) + (gk - 256);
            ph_ = A2h; pl_ = A2l;
          }
          vh = *(const uint4*)&ph_[idx];
          vl = *(const uint4*)&pl_[idx];
        }
      } else {
        if (gm < M && gk < K) {
          const int ox = gm % W, t_ = gm / W;
          const int oy = t_ % H, b = t_ / H;
          const int e = gk >> icb, ic = gk & (IC - 1);
          const int ky = e / 3, kx = e - 3 * (e / 3);
          const int iy = oy + ky - 1, ix = ox + kx - 1;
          if (iy >= 0 && iy < H && ix >= 0 && ix < W) {
            const size_t idx = (((size_t)b * H + iy) * W + ix) * IC + ic;
            vh = *(const uint4*)&Ah[idx];
            vl = *(const uint4*)&Al[idx];
          }
        }
      }
      *(uint4*)&Ash[row][kc] = vh;
      *(uint4*)&Asl[row][kc] = vl;
    }
#pragma unroll
    for (int s = 0; s < 2; ++s) {
      const int cc = s * 256 + tid;
      const int row = cc >> 3, kc = (cc & 7) << 3;
      const int gk = k0 + kc;
      uint4 vh = {0u, 0u, 0u, 0u}, vl = {0u, 0u, 0u, 0u};
      if (gk < K) {
        vh = *(const uint4*)&Bh[(size_t)(n0 + row) * K + gk];
        vl = *(const uint4*)&Bl[(size_t)(n0 + row) * K + gk];
      }
      *(uint4*)&Bsh[row][kc] = vh;
      *(uint4*)&Bsl[row][kc] = vl;
    }
    __syncthreads();
#pragma unroll
    for (int kk = 0; kk < 64; kk += 32) {
      const int ko = kk + ((lane >> 4) << 3);
      const int ra0 = wy * 32 + (lane & 15), ra1 = ra0 + 16;
      const int rb0 = wx * 32 + (lane & 15), rb1 = rb0 + 16;
      bf16x8v a0h = *(const bf16x8v*)&Ash[ra0][ko];
      bf16x8v a1h = *(const bf16x8v*)&Ash[ra1][ko];
      bf16x8v b0h = *(const bf16x8v*)&Bsh[rb0][ko];
      bf16x8v b1h = *(const bf16x8v*)&Bsh[rb1][ko];
      bf16x8v a0l = *(const bf16x8v*)&Asl[ra0][ko];
      bf16x8v a1l = *(const bf16x8v*)&Asl[ra1][ko];
      bf16x8v b0l = *(const bf16x8v*)&Bsl[rb0][ko];
      bf16x8v b1l = *(const bf16x8v*)&Bsl[rb1][ko];
      acc[0][0] = __builtin_amdgcn_mfma_f32_16x16x32_bf16(a0h, b0h, acc[0][0], 0, 0, 0);
      acc[0][1] = __builtin_amdgcn_mfma_f32_16x16x32_bf16(a0h, b1h, acc[0][1], 0, 0, 0);
      acc[1][0] = __builtin_amdgcn_mfma_f32_16x16x32_bf16(a1h, b0h, acc[1][0], 0, 0, 0);
      acc[1][1] = __builtin_amdgcn_mfma_f32_16x16x32_bf16(a1h, b1h, acc[1][1], 0, 0, 0);
      acc[0][0] = __builtin_amdgcn_mfma_f32_16x16x32_bf16(a0h, b0l, acc[0][0], 0, 0, 0);
      acc[0][1] = __builtin_amdgcn_mfma_f32_16x16x32_bf16(a0h, b1l, acc[0][1], 0, 0, 0);
      acc[1][0] = __builtin_amdgcn_mfma_f32_16x16x32_bf16(a1h, b0l, acc[1][0], 0, 0, 0);
      acc[1][1] = __builtin_amdgcn_mfma_f32_16x16x32_bf16(a1h, b1l, acc[1][1], 0, 0, 0);
      acc[0][0] = __builtin_amdgcn_mfma_f32_16x16x32_bf16(a0l, b0h, acc[0][0], 0, 0, 0);
      acc[0][1] = __builtin_amdgcn_mfma_f32_16x16x32_bf16(a0l, b1h, acc[0][1], 0, 0, 0);
      acc[1][0] = __builtin_amdgcn_mfma_f32_16x16x32_bf16(a1l, b0h, acc[1][0], 0, 0, 0);
      acc[1][1] = __builtin_amdgcn_mfma_f32_16x16x32_bf16(a1l, b1h, acc[1][1], 0, 0, 0);
    }
    __syncthreads();
  }
#pragma unroll
  for (int r = 0; r < 2; ++r) {
#pragma unroll
    for (int cI = 0; cI < 2; ++cI) {
      const int gn = n0 + wx * 32 + cI * 16 + (lane & 15);
      float sc0 = 0.f, sh0 = 0.f;
      if (EPI == 0) { sc0 = p1[gn] * BN_INV; sh0 = p2[gn]; }
#pragma unroll
      for (int i = 0; i < 4; ++i) {
        const int gm = m0 + wy * 32 + r * 16 + ((lane >> 4) << 2) + i;
        if (gm >= M) continue;
        const float a = acc[r][cI][i];
        if (EPI == 0) {
          Cout[(size_t)gm * ldc + gn] = fmaxf((a + p0[gn]) * sc0 + sh0, 0.f);
        } else {
          Cout[(size_t)gm * ldc + gn] = a + p0[gn];
        }
      }
    }
  }
}

// ---------------- fused attention, block = (q,s,t-group of 7) ---------------
// r21: 384 threads -> score phase single pass (343 items; was 256+87
// imbalanced 2-pass). PV guarded to tid<256. Rest identical to r10/r19.
__global__ __launch_bounds__(384) void attention_f32(
    const float* __restrict__ proj, const u16* __restrict__ featTh,
    const u16* __restrict__ featTl, u16* __restrict__ atth,
    u16* __restrict__ attl) {
  __shared__ float WqT[64][9];
  __shared__ float WhT[64][51];
  __shared__ float sc[7][64];
  const int bid = blockIdx.x;
  const int qs = bid / 7, tg = bid - 7 * qs;
  const int q = qs / NS, s = qs - NS * q;
  const int tid = threadIdx.x;
  const float* pq = proj + ((size_t)(NS + q) * T49 + tg * 7) * 64;
  const float* ph = proj + (size_t)s * T49 * 64;
  for (int l = tid; l < 7 * 64; l += 384) WqT[l & 63][l >> 6] = pq[l];
  for (int l = tid; l < T49 * 64; l += 384) WhT[l & 63][l >> 6] = ph[l];
  __syncthreads();
  constexpr float C2LOG2E = 2.8853900817779268f;
  if (tid < 343) {
    const int tl = tid / 49, u = tid - 49 * tl;
    float a0 = 0.f, a1 = 0.f, a2 = 0.f, a3 = 0.f;
#pragma unroll
    for (int h = 0; h < 64; h += 4) {
      const float p0 = WqT[h + 0][tl] * WhT[h + 0][u];
      const float p1 = WqT[h + 1][tl] * WhT[h + 1][u];
      const float p2 = WqT[h + 2][tl] * WhT[h + 2][u];
      const float p3 = WqT[h + 3][tl] * WhT[h + 3][u];
      a0 += 1.f - 2.f * __builtin_amdgcn_rcpf(__builtin_amdgcn_exp2f(p0 * C2LOG2E) + 1.f);
      a1 += 1.f - 2.f * __builtin_amdgcn_rcpf(__builtin_amdgcn_exp2f(p1 * C2LOG2E) + 1.f);
      a2 += 1.f - 2.f * __builtin_amdgcn_rcpf(__builtin_amdgcn_exp2f(p2 * C2LOG2E) + 1.f);
      a3 += 1.f - 2.f * __builtin_amdgcn_rcpf(__builtin_amdgcn_exp2f(p3 * C2LOG2E) + 1.f);
    }
    sc[tl][u] = (a0 + a1) + (a2 + a3);
  }
  __syncthreads();
  if (tid < 56) {
    const int t = tid >> 3, g = tid & 7;
    float m = -3.4e38f;
    for (int u = g; u < T49; u += 8) m = fmaxf(m, sc[t][u]);
    m = fmaxf(m, __shfl_xor(m, 4));
    m = fmaxf(m, __shfl_xor(m, 2));
    m = fmaxf(m, __shfl_xor(m, 1));
    float ssum = 0.f;
    for (int u = g; u < T49; u += 8) {
      const float e = __builtin_amdgcn_exp2f((sc[t][u] - m) * LOG2E);
      sc[t][u] = e; ssum += e;
    }
    ssum += __shfl_xor(ssum, 4);
    ssum += __shfl_xor(ssum, 2);
    ssum += __shfl_xor(ssum, 1);
    const float inv = 1.f / ssum;
    for (int u = g; u < T49; u += 8) sc[t][u] *= inv;
  }
  __syncthreads();
  if (tid < 256) {
    const u16* fsh = featTh + (size_t)s * T49 * 256;
    const u16* fsl = featTl + (size_t)s * T49 * 256;
    const size_t obase = ((size_t)qs * T49 + tg * 7) * 256;
    float acc[7] = {0.f, 0.f, 0.f, 0.f, 0.f, 0.f, 0.f};
    for (int u = 0; u < T49; ++u) {
      const float v = b2f(fsh[u * 256 + tid]) + b2f(fsl[u * 256 + tid]);
#pragma unroll
      for (int i = 0; i < 7; ++i) acc[i] += sc[i][u] * v;
    }
#pragma unroll
    for (int i = 0; i < 7; ++i) {
      const float a = acc[i];
      const u16 h = f2b(a);
      atth[obase + (size_t)i * 256 + tid] = h;
      attl[obase + (size_t)i * 256 + tid] = f2b(a - b2f(h));
    }
  }
}

// ---------------- batched MFMA GRU (r16 structure, 53.5us measured) ---------
constexpr int SPB = 8;
__global__ __launch_bounds__(512) void gru_mfma(
    const float* __restrict__ gi,
    const float* __restrict__ wh,
    const float* __restrict__ bh,
    u16* __restrict__ yh, u16* __restrict__ yl,
    float* __restrict__ hfin,
    int store_all) {
  __shared__ u16 hah[16][136];
  __shared__ float ghs[SPB][384];
  __shared__ float hfl[SPB][128];
  const int tid = threadIdx.x;
  const int lane = tid & 63, wv = tid >> 6;
  const int r0 = blockIdx.x * SPB;
  bf16x8v Bhr[3][4], Blr[3][4];
#pragma unroll
  for (int f = 0; f < 3; ++f) {
    const int n = (wv * 3 + f) * 16 + (lane & 15);
#pragma unroll
    for (int kk = 0; kk < 4; ++kk) {
      const int k = kk * 32 + ((lane >> 4) << 3);
      const float* p = wh + (size_t)n * 128 + k;
      float v[8];
      *(float4*)&v[0] = *(const float4*)p;
      *(float4*)&v[4] = *(const float4*)(p + 4);
      u32 hp[4], lp[4];
      split8(v, hp, lp);
      Bhr[f][kk] = *(bf16x8v*)hp;
      Blr[f][kk] = *(bf16x8v*)lp;
    }
  }
  const int row0 = tid >> 7, j0 = tid & 127;
  const int row1 = (512 + tid) >> 7, j1 = tid & 127;
  int sq0 = r0 + row0; if (sq0 >= B3) sq0 = B3 - 1;
  int sq1 = r0 + row1; if (sq1 >= B3) sq1 = B3 - 1;
  const float bhr0 = bh[j0], bhz0 = bh[128 + j0], bhn0 = bh[256 + j0];
  const float bhr1 = bh[j1], bhz1 = bh[128 + j1], bhn1 = bh[256 + j1];
  const float* gib0 = gi + (size_t)sq0 * T49 * 384;
  const float* gib1 = gi + (size_t)sq1 * T49 * 384;
  for (int i = tid; i < 16 * 136; i += 512) hah[i / 136][i % 136] = 0;
  for (int i = tid; i < SPB * 128; i += 512) hfl[i >> 7][i & 127] = 0.f;
  __syncthreads();
  const int ar = lane & 15, ko = (lane >> 4) << 3;
  float xr0c = gib0[j0], xz0c = gib0[128 + j0], xn0c = gib0[256 + j0];
  float xr1c = gib1[j1], xz1c = gib1[128 + j1], xn1c = gib1[256 + j1];
  for (int t = 0; t < T49; ++t) {
    const int tn = (t + 1 < T49) ? t + 1 : t;
    const float* g0n = gib0 + (size_t)tn * 384;
    const float* g1n = gib1 + (size_t)tn * 384;
    const float xr0n = g0n[j0], xz0n = g0n[128 + j0], xn0n = g0n[256 + j0];
    const float xr1n = g1n[j1], xz1n = g1n[128 + j1], xn1n = g1n[256 + j1];
    bf16x8v Ah[4];
#pragma unroll
    for (int kk = 0; kk < 4; ++kk)
      Ah[kk] = *(const bf16x8v*)&hah[ar][kk * 32 + ko];
#pragma unroll
    for (int f = 0; f < 3; ++f) {
      f32x4 acc = {0, 0, 0, 0};
#pragma unroll
      for (int kk = 0; kk < 4; ++kk)
        acc = __builtin_amdgcn_mfma_f32_16x16x32_bf16(Ah[kk], Bhr[f][kk], acc, 0, 0, 0);
#pragma unroll
      for (int kk = 0; kk < 4; ++kk)
        acc = __builtin_amdgcn_mfma_f32_16x16x32_bf16(Ah[kk], Blr[f][kk], acc, 0, 0, 0);
      const int nc = (wv * 3 + f) * 16 + (lane & 15);
      const int rb = (lane >> 4) << 2;
      if (rb < SPB) {
#pragma unroll
        for (int i = 0; i < 4; ++i) ghs[rb + i][nc] = acc[i];
      }
    }
    __syncthreads();
    {
      const float r_ = fsigmoid(xr0c + ghs[row0][j0] + bhr0);
      const float z_ = fsigmoid(xz0c + ghs[row0][128 + j0] + bhz0);
      const float n_ = ftanh(xn0c + r_ * (ghs[row0][256 + j0] + bhn0));
      const float hn = (1.f - z_) * n_ + z_ * hfl[row0][j0];
      hfl[row0][j0] = hn;
      const u16 hb = f2b(hn);
      hah[row0][j0] = hb;
      if (r0 + row0 < B3) {
        if (store_all) {
          const size_t o = ((size_t)(r0 + row0) * T49 + t) * 128 + j0;
          yh[o] = hb;
          yl[o] = f2b(hn - b2f(hb));
        } else if (t == T49 - 1) {
          hfin[(size_t)(r0 + row0) * 128 + j0] = hn;
        }
      }
    }
    {
      const float r_ = fsigmoid(xr1c + ghs[row1][j1] + bhr1);
      const float z_ = fsigmoid(xz1c + ghs[row1][128 + j1] + bhz1);
      const float n_ = ftanh(xn1c + r_ * (ghs[row1][256 + j1] + bhn1));
      const float hn = (1.f - z_) * n_ + z_ * hfl[row1][j1];
      hfl[row1][j1] = hn;
      const u16 hb = f2b(hn);
      hah[row1][j1] = hb;
      if (r0 + row1 < B3) {
        if (store_all) {
          const size_t o = ((size_t)(r0 + row1) * T49 + t) * 128 + j1;
          yh[o] = hb;
          yl[o] = f2b(hn - b2f(hb));
        } else if (t == T49 - 1) {
          hfin[(size_t)(r0 + row1) * 128 + j1] = hn;
        }
      }
    }
    __syncthreads();
    xr0c = xr0n; xz0c = xz0n; xn0c = xn0n;
    xr1c = xr1n; xz1c = xz1n; xn1c = xn1n;
  }
}

// ---------------- head ----------------
__global__ __launch_bounds__(512) void head_kernel(
    const float* __restrict__ hf, const float* __restrict__ tw,
    const float* __restrict__ tb, float* __restrict__ out) {
  __shared__ float lg[B3];
  const int tid = threadIdx.x;
  if (tid < B3) {
    const float* h = hf + (size_t)tid * 128;
    float acc = tb[0];
    for (int k = 0; k < 128; ++k) acc += h[k] * tw[k];
    lg[tid] = acc;
  }
  __syncthreads();
  if (tid < NQ) {
    float cls[5];
#pragma unroll
    for (int n = 0; n < 5; ++n) {
      float s = 0.f;
#pragma unroll
      for (int k = 0; k < 5; ++k) s += lg[tid * 25 + n * 5 + k];
      cls[n] = s;
    }
    float m = cls[0];
#pragma unroll
    for (int n = 1; n < 5; ++n) m = fmaxf(m, cls[n]);
    float se = 0.f;
#pragma unroll
    for (int n = 0; n < 5; ++n) se += expf(cls[n] - m);
    const float lse = m + logf(se);
#pragma unroll
    for (int n = 0; n < 5; ++n) out[tid * 5 + n] = cls[n] - lse;
  }
}

extern "C" void kernel_launch(void* const* d_in, const int* in_sizes, int n_in,
                              void* d_out, int out_size, void* d_ws,
                              size_t ws_size, hipStream_t stream) {
  (void)in_sizes; (void)n_in; (void)out_size; (void)ws_size;
  const float* support = (const float*)d_in[0];
  const float* query   = (const float*)d_in[1];
  const float* cw1 = (const float*)d_in[2];  const float* cb1 = (const float*)d_in[3];
  const float* cw2 = (const float*)d_in[4];  const float* cb2 = (const float*)d_in[5];
  const float* cw3 = (const float*)d_in[6];  const float* cb3 = (const float*)d_in[7];
  const float* cw4 = (const float*)d_in[8];  const float* cb4 = (const float*)d_in[9];
  const float* g1  = (const float*)d_in[10]; const float* be1 = (const float*)d_in[11];
  const float* g2  = (const float*)d_in[12]; const float* be2 = (const float*)d_in[13];
  const float* g3  = (const float*)d_in[14]; const float* be3 = (const float*)d_in[15];
  const float* g4  = (const float*)d_in[16]; const float* be4 = (const float*)d_in[17];
  const float* aw  = (const float*)d_in[18]; const float* ab  = (const float*)d_in[19];
  const float* wi0 = (const float*)d_in[20]; const float* wh0 = (const float*)d_in[21];
  const float* bi0 = (const float*)d_in[22]; const float* bh0 = (const float*)d_in[23];
  const float* wi1 = (const float*)d_in[24]; const float* wh1 = (const float*)d_in[25];
  const float* bi1 = (const float*)d_in[26]; const float* bh1 = (const float*)d_in[27];
  const float* tw  = (const float*)d_in[28]; const float* tb  = (const float*)d_in[29];

  char* ws = (char*)d_ws;
  float* out = (float*)d_out;
  u16* A1H    = (u16*)(ws + A1H_OFF);
  u16* A1L    = (u16*)(ws + A1L_OFF);
  float* X2   = (float*)(ws + X2_OFF);
  u16* P2H    = (u16*)(ws + P2H_OFF);
  u16* P2L    = (u16*)(ws + P2L_OFF);
  float* X3   = (float*)(ws + X3_OFF);
  u16* P3H    = (u16*)(ws + P3H_OFF);
  u16* P3L    = (u16*)(ws + P3L_OFF);
  float* X4   = (float*)(ws + X4_OFF);
  u16* FEATTH = (u16*)(ws + FEATTH_OFF);
  u16* FEATTL = (u16*)(ws + FEATTL_OFF);
  float* PROJ = (float*)(ws + PROJ_OFF);
  u16* ATTH   = (u16*)(ws + ATTH_OFF);
  u16* ATTL   = (u16*)(ws + ATTL_OFF);
  float* GI   = (float*)(ws + GI_OFF);
  u16* Y0H    = (u16*)(ws + Y0H_OFF);
  u16* Y0L    = (u16*)(ws + Y0L_OFF);
  float* HFIN = (float*)(ws + HFIN_OFF);
  u16* WBH = (u16*)(ws + WBH_OFF);
  u16* WBL = (u16*)(ws + WBL_OFF);

  // weight conversions (single fused launch)
  cvt_all<<<(CVT_N + 255) / 256, 256, 0, stream>>>(cw2, cw3, cw4, aw, wi0, wi1, WBH, WBL);

  // ---- encoder ----
  conv1_pool<<<15680, 256, 0, stream>>>(support, query, cw1, cb1, g1, be1, A1H, A1L);
  sgemm<2, 0><<<dim3(1, 1960), 256, 0, stream>>>(
      A1H, A1L, nullptr, nullptr, 125440, 288, WBH + W2_E, WBL + W2_E,
      cb2, g2, be2, X2, 64, 56, 56, 32, 5);
  maxpool2_split<<<1960, 256, 0, stream>>>(X2, P2H, P2L, NB, 56, 56, 64);
  sgemm<2, 0><<<dim3(2, 490), 256, 0, stream>>>(
      P2H, P2L, nullptr, nullptr, 31360, 576, WBH + W3_E, WBL + W3_E,
      cb3, g3, be3, X3, 128, 28, 28, 64, 6);
  maxpool2_split<<<980, 256, 0, stream>>>(X3, P3H, P3L, NB, 28, 28, 128);
  sgemm<2, 0><<<dim3(4, 123), 256, 0, stream>>>(
      P3H, P3L, nullptr, nullptr, 7840, 1152, WBH + W4_E, WBL + W4_E,
      cb4, g4, be4, X4, 256, 14, 14, 128, 7);
  maxpool2_split<<<490, 256, 0, stream>>>(X4, FEATTH, FEATTL, NB, 14, 14, 256);

  // ---- attention ----
  sgemm<0, 1><<<dim3(1, 31), 256, 0, stream>>>(
      FEATTH, FEATTL, nullptr, nullptr, NB * T49, 256, WBH + AW_E, WBL + AW_E,
      ab, nullptr, nullptr, PROJ, 64, 0, 0, 0, 0);
  attention_f32<<<B3 * 7, 384, 0, stream>>>(PROJ, FEATTH, FEATTL, ATTH, ATTL);

  // ---- GRU stack ----
  sgemm<1, 1><<<dim3(6, 288), 256, 0, stream>>>(
      ATTH, ATTL, FEATTH, FEATTL, B3 * T49, 512, WBH + WI0_E, WBL + WI0_E,
      bi0, nullptr, nullptr, GI, 384, 0, 0, 0, 0);
  gru_mfma<<<47, 512, 0, stream>>>(GI, wh0, bh0, Y0H, Y0L, nullptr, 1);
  sgemm<0, 1><<<dim3(6, 288), 256, 0, stream>>>(
      Y0H, Y0L, nullptr, nullptr, B3 * T49, 128, WBH + WI1_E, WBL + WI1_E,
      bi1, nullptr, nullptr, GI, 384, 0, 0, 0, 0);
  gru_mfma<<<47, 512, 0, stream>>>(GI, wh1, bh1, nullptr, nullptr, HFIN, 0);

  // ---- head ----
  head_kernel<<<1, 512, 0, stream>>>(HFIN, tw, tb, out);
}

// Round 22
// 368.112 us; speedup vs baseline: 1.1074x; 1.0012x over previous
//
#include <hip/hip_runtime.h>
#include <hip/hip_bf16.h>
#include <math.h>

typedef unsigned short u16;
typedef unsigned int u32;
typedef __attribute__((ext_vector_type(8))) short bf16x8v;
typedef __attribute__((ext_vector_type(4))) float f32x4;

// ---------------- problem constants ----------------
constexpr int NS = 25, NQ = 15, NB = 40;
constexpr int B3 = 375;     // 15*25
constexpr int T49 = 49;
constexpr float BN_INV = 0.9999950000374997f;

// ---------------- workspace layout (BYTES) ----------------------------------
constexpr size_t A1H_OFF    = 0;
constexpr size_t A1L_OFF    = 8028160;
constexpr size_t X2_OFF     = 16056320;
constexpr size_t P2H_OFF    = 48168960;
constexpr size_t P2L_OFF    = 52183040;
constexpr size_t X3_OFF     = 0;
constexpr size_t P3H_OFF    = 56197120;
constexpr size_t P3L_OFF    = 58204160;
constexpr size_t X4_OFF     = 0;
constexpr size_t FEATTH_OFF = 60211200;
constexpr size_t FEATTL_OFF = 61214720;
constexpr size_t PROJ_OFF   = 0;            // f32 501,760 B
constexpr size_t QG_OFF     = 1048576;      // f32 735*384 = 1,128,960 B (dead X3/X4 zone)
constexpr size_t ATTH_OFF   = 16056320;
constexpr size_t ATTL_OFF   = 25464320;
constexpr size_t GI_OFF     = 62218240;
constexpr size_t Y0H_OFF    = 0;
constexpr size_t Y0L_OFF    = 4704000;
constexpr size_t HFIN_OFF   = 90442240;
constexpr size_t WBH_OFF    = 91027456;     // arena now 845,824 u16 = 1,691,648 B
constexpr size_t WBL_OFF    = 92719104;
// u16-element offsets within each weight arena:
constexpr size_t W2_E = 0;
constexpr size_t W3_E = 18432;
constexpr size_t W4_E = 92160;
constexpr size_t AW_E = 387072;
constexpr size_t WI0_E = 403456;   // full 384x512 (kept; unused by GEMMs now)
constexpr size_t WI1_E = 600064;   // 384x128
constexpr int    CVT_N = 649216;   // end of original concat
constexpr size_t WI0A_E = 649216;  // 384x256, k<256
constexpr size_t WI0B_E = 747520;  // 384x256, k>=256
constexpr int    CVT_N2 = 845824;  // total arena elements

static __device__ __forceinline__ u16 f2b(float f) {
  __hip_bfloat16 h = __float2bfloat16(f);
  return *reinterpret_cast<u16*>(&h);
}
static __device__ __forceinline__ float b2f(u16 u) {
  return __uint_as_float((u32)u << 16);
}
constexpr float LOG2E = 1.4426950408889634f;
static __device__ __forceinline__ float fsigmoid(float x) {
  return __builtin_amdgcn_rcpf(1.f + __builtin_amdgcn_exp2f(-x * LOG2E));
}
static __device__ __forceinline__ float ftanh(float x) {
  return 1.f - 2.f * __builtin_amdgcn_rcpf(__builtin_amdgcn_exp2f(x * (2.f * LOG2E)) + 1.f);
}
static __device__ __forceinline__ void split8(const float* v, u32* hp, u32* lp) {
  u16 h[8], l[8];
#pragma unroll
  for (int j = 0; j < 8; ++j) {
    const u16 hb = f2b(v[j]);
    h[j] = hb;
    l[j] = f2b(v[j] - b2f(hb));
  }
#pragma unroll
  for (int j = 0; j < 4; ++j) {
    hp[j] = (u32)h[2 * j] | ((u32)h[2 * j + 1] << 16);
    lp[j] = (u32)l[2 * j] | ((u32)l[2 * j + 1] << 16);
  }
}

// ---------------- fused weight converter (1 launch) ----------------
// r22: also emits wi0 split into two 384x256 halves (contiguous-K layouts for
// the qrep-split gemm0). Values identical to the full wi0 copy.
__global__ void cvt_all(const float* __restrict__ cw2, const float* __restrict__ cw3,
                        const float* __restrict__ cw4, const float* __restrict__ aw,
                        const float* __restrict__ wi0, const float* __restrict__ wi1,
                        u16* __restrict__ oh, u16* __restrict__ ol) {
  const int i = blockIdx.x * 256 + threadIdx.x;
  if (i >= CVT_N2) return;
  float v;
  if (i < (int)W3_E) {
    const int l = i, oc = l / 288, rem = l - oc * 288, e = rem >> 5, ic = rem & 31;
    v = cw2[((size_t)(oc * 32 + ic) * 3 + e / 3) * 3 + e % 3];
  } else if (i < (int)W4_E) {
    const int l = i - (int)W3_E, oc = l / 576, rem = l - oc * 576, e = rem >> 6, ic = rem & 63;
    v = cw3[((size_t)(oc * 64 + ic) * 3 + e / 3) * 3 + e % 3];
  } else if (i < (int)AW_E) {
    const int l = i - (int)W4_E, oc = l / 1152, rem = l - oc * 1152, e = rem >> 7, ic = rem & 127;
    v = cw4[((size_t)(oc * 128 + ic) * 3 + e / 3) * 3 + e % 3];
  } else if (i < (int)WI0_E) {
    v = aw[i - (int)AW_E];
  } else if (i < (int)WI1_E) {
    v = wi0[i - (int)WI0_E];
  } else if (i < CVT_N) {
    v = wi1[i - (int)WI1_E];
  } else if (i < (int)WI0B_E) {           // wi0a: k < 256
    const int l = i - (int)WI0A_E, j = l >> 8, k = l & 255;
    v = wi0[(size_t)j * 512 + k];
  } else {                                 // wi0b: k >= 256
    const int l = i - (int)WI0B_E, j = l >> 8, k = l & 255;
    v = wi0[(size_t)j * 512 + 256 + k];
  }
  const u16 h = f2b(v);
  oh[i] = h;
  ol[i] = f2b(v - b2f(h));
}

// ---------------- fused conv1(s2)+BN+ReLU+pool2 -> bf16 hi/lo NHWC ----------
__global__ __launch_bounds__(256) void conv1_pool(
    const float* __restrict__ support, const float* __restrict__ query,
    const float* __restrict__ w1, const float* __restrict__ cb1,
    const float* __restrict__ g1, const float* __restrict__ be1,
    u16* __restrict__ outh, u16* __restrict__ outl) {
  __shared__ float wl[288], scl[32], shl[32], cbl[32];
  const int tid = threadIdx.x;
  for (int l = tid; l < 288; l += 256) wl[l] = w1[l];
  if (tid < 32) { scl[tid] = g1[tid] * BN_INV; shl[tid] = be1[tid]; cbl[tid] = cb1[tid]; }
  __syncthreads();
  const int oc = tid & 31;
  const int p = blockIdx.x * 8 + (tid >> 5);
  const int ox = p % 56, oy = (p / 56) % 56, b = p / 3136;
  const float* in_b = (b < NS) ? (support + (size_t)b * 50176)
                               : (query + (size_t)(b - NS) * 50176);
  const int iy0 = 4 * oy - 1, ix0 = 4 * ox - 1;
  float pat[5][5];
#pragma unroll
  for (int dy = 0; dy < 5; ++dy) {
    const int iy = iy0 + dy;
#pragma unroll
    for (int dx = 0; dx < 5; ++dx) {
      const int ix = ix0 + dx;
      pat[dy][dx] = (iy >= 0 && iy < 224 && ix >= 0 && ix < 224)
                        ? in_b[(size_t)iy * 224 + ix] : 0.f;
    }
  }
  const float* wp = &wl[oc * 9];
  float mx = 0.f;
#pragma unroll
  for (int py = 0; py < 2; ++py)
#pragma unroll
    for (int px = 0; px < 2; ++px) {
      float acc = 0.f;
#pragma unroll
      for (int ky = 0; ky < 3; ++ky)
#pragma unroll
        for (int kx = 0; kx < 3; ++kx)
          acc += pat[2 * py + ky][2 * px + kx] * wp[ky * 3 + kx];
      float v = (acc + cbl[oc]) * scl[oc] + shl[oc];
      mx = fmaxf(mx, v);
    }
  const u16 h = f2b(mx);
  outh[(size_t)p * 32 + oc] = h;
  outl[(size_t)p * 32 + oc] = f2b(mx - b2f(h));
}

// ---------------- f32 NHWC maxpool 2x2 -> bf16 hi/lo planes -----------------
__global__ void maxpool2_split(const float* __restrict__ X, u16* __restrict__ Yh,
                               u16* __restrict__ Yl, int Bn, int H, int W, int C) {
  const int OH = H >> 1, OW = W >> 1;
  const int cpr = C >> 2;
  const int chunks = Bn * OH * OW * cpr;
  for (int i = blockIdx.x * blockDim.x + threadIdx.x; i < chunks;
       i += gridDim.x * blockDim.x) {
    const int c4 = i % cpr, m = i / cpr;
    const int ox = m % OW, oy = (m / OW) % OH, b = m / (OW * OH);
    const size_t base = (((size_t)b * H + 2 * oy) * W + 2 * ox) * C + (c4 << 2);
    const float4 r0 = *(const float4*)&X[base];
    const float4 r1 = *(const float4*)&X[base + C];
    const float4 r2 = *(const float4*)&X[base + (size_t)W * C];
    const float4 r3 = *(const float4*)&X[base + (size_t)W * C + C];
    float o[4];
    o[0] = fmaxf(fmaxf(r0.x, r1.x), fmaxf(r2.x, r3.x));
    o[1] = fmaxf(fmaxf(r0.y, r1.y), fmaxf(r2.y, r3.y));
    o[2] = fmaxf(fmaxf(r0.z, r1.z), fmaxf(r2.z, r3.z));
    o[3] = fmaxf(fmaxf(r0.w, r1.w), fmaxf(r2.w, r3.w));
    u16 hh[4], ll[4];
#pragma unroll
    for (int j = 0; j < 4; ++j) {
      hh[j] = f2b(o[j]);
      ll[j] = f2b(o[j] - b2f(hh[j]));
    }
    const size_t off = (size_t)m * C + (c4 << 2);
    uint2 vh, vl;
    vh.x = (u32)hh[0] | ((u32)hh[1] << 16); vh.y = (u32)hh[2] | ((u32)hh[3] << 16);
    vl.x = (u32)ll[0] | ((u32)ll[1] << 16); vl.y = (u32)ll[2] | ((u32)ll[3] << 16);
    *(uint2*)&Yh[off] = vh;
    *(uint2*)&Yl[off] = vl;
  }
}

// ---------------- 64x64-tile split-bf16 MFMA GEMM ---------------------------
// EPI 0: relu((acc+p0[n])*p1s[n]*BN_INV + p2[n]) -> f32
// EPI 1: acc + p0[n] -> f32
// EPI 2: acc + QG[(q(m)*49+t(m))*384+n] -> f32   (qrep-split gemm0; QG via p1)
template <int AMODE, int EPI>
__global__ __launch_bounds__(256) void sgemm(
    const u16* __restrict__ Ah, const u16* __restrict__ Al,
    const u16* __restrict__ A2h, const u16* __restrict__ A2l, int M, int K,
    const u16* __restrict__ Bh, const u16* __restrict__ Bl,
    const float* __restrict__ p0, const float* __restrict__ p1,
    const float* __restrict__ p2, float* __restrict__ Cout, int ldc,
    int H, int W, int IC, int icb) {
  __shared__ u16 Ash[64][72], Asl[64][72];
  __shared__ u16 Bsh[64][72], Bsl[64][72];
  const int tid = threadIdx.x;
  const int lane = tid & 63, wv = tid >> 6;
  const int wy = wv >> 1, wx = wv & 1;
  const int n0 = blockIdx.x * 64, m0 = blockIdx.y * 64;
  f32x4 acc[2][2] = {{{0, 0, 0, 0}, {0, 0, 0, 0}}, {{0, 0, 0, 0}, {0, 0, 0, 0}}};
  for (int k0 = 0; k0 < K; k0 += 64) {
#pragma unroll
    for (int s = 0; s < 2; ++s) {
      const int cc = s * 256 + tid;
      const int row = cc >> 3, kc = (cc & 7) << 3;
      const int gm = m0 + row, gk = k0 + kc;
      uint4 vh = {0u, 0u, 0u, 0u}, vl = {0u, 0u, 0u, 0u};
      if (AMODE == 0) {
        if (gm < M && gk < K) {
          const size_t idx = (size_t)gm * K + gk;
          vh = *(const uint4*)&Ah[idx];
          vl = *(const uint4*)&Al[idx];
        }
      } else {
        if (gm < M && gk < K) {
          const int ox = gm % W, t_ = gm / W;
          const int oy = t_ % H, b = t_ / H;
          const int e = gk >> icb, ic = gk & (IC - 1);
          const int ky = e / 3, kx = e - 3 * (e / 3);
          const int iy = oy + ky - 1, ix = ox + kx - 1;
          if (iy >= 0 && iy < H && ix >= 0 && ix < W) {
            const size_t idx = (((size_t)b * H + iy) * W + ix) * IC + ic;
            vh = *(const uint4*)&Ah[idx];
            vl = *(const uint4*)&Al[idx];
          }
        }
      }
      *(uint4*)&Ash[row][kc] = vh;
      *(uint4*)&Asl[row][kc] = vl;
    }
#pragma unroll
    for (int s = 0; s < 2; ++s) {
      const int cc = s * 256 + tid;
      const int row = cc >> 3, kc = (cc & 7) << 3;
      const int gk = k0 + kc;
      uint4 vh = {0u, 0u, 0u, 0u}, vl = {0u, 0u, 0u, 0u};
      if (gk < K) {
        vh = *(const uint4*)&Bh[(size_t)(n0 + row) * K + gk];
        vl = *(const uint4*)&Bl[(size_t)(n0 + row) * K + gk];
      }
      *(uint4*)&Bsh[row][kc] = vh;
      *(uint4*)&Bsl[row][kc] = vl;
    }
    __syncthreads();
#pragma unroll
    for (int kk = 0; kk < 64; kk += 32) {
      const int ko = kk + ((lane >> 4) << 3);
      const int ra0 = wy * 32 + (lane & 15), ra1 = ra0 + 16;
      const int rb0 = wx * 32 + (lane & 15), rb1 = rb0 + 16;
      bf16x8v a0h = *(const bf16x8v*)&Ash[ra0][ko];
      bf16x8v a1h = *(const bf16x8v*)&Ash[ra1][ko];
      bf16x8v b0h = *(const bf16x8v*)&Bsh[rb0][ko];
      bf16x8v b1h = *(const bf16x8v*)&Bsh[rb1][ko];
      bf16x8v a0l = *(const bf16x8v*)&Asl[ra0][ko];
      bf16x8v a1l = *(const bf16x8v*)&Asl[ra1][ko];
      bf16x8v b0l = *(const bf16x8v*)&Bsl[rb0][ko];
      bf16x8v b1l = *(const bf16x8v*)&Bsl[rb1][ko];
      acc[0][0] = __builtin_amdgcn_mfma_f32_16x16x32_bf16(a0h, b0h, acc[0][0], 0, 0, 0);
      acc[0][1] = __builtin_amdgcn_mfma_f32_16x16x32_bf16(a0h, b1h, acc[0][1], 0, 0, 0);
      acc[1][0] = __builtin_amdgcn_mfma_f32_16x16x32_bf16(a1h, b0h, acc[1][0], 0, 0, 0);
      acc[1][1] = __builtin_amdgcn_mfma_f32_16x16x32_bf16(a1h, b1h, acc[1][1], 0, 0, 0);
      acc[0][0] = __builtin_amdgcn_mfma_f32_16x16x32_bf16(a0h, b0l, acc[0][0], 0, 0, 0);
      acc[0][1] = __builtin_amdgcn_mfma_f32_16x16x32_bf16(a0h, b1l, acc[0][1], 0, 0, 0);
      acc[1][0] = __builtin_amdgcn_mfma_f32_16x16x32_bf16(a1h, b0l, acc[1][0], 0, 0, 0);
      acc[1][1] = __builtin_amdgcn_mfma_f32_16x16x32_bf16(a1h, b1l, acc[1][1], 0, 0, 0);
      acc[0][0] = __builtin_amdgcn_mfma_f32_16x16x32_bf16(a0l, b0h, acc[0][0], 0, 0, 0);
      acc[0][1] = __builtin_amdgcn_mfma_f32_16x16x32_bf16(a0l, b1h, acc[0][1], 0, 0, 0);
      acc[1][0] = __builtin_amdgcn_mfma_f32_16x16x32_bf16(a1l, b0h, acc[1][0], 0, 0, 0);
      acc[1][1] = __builtin_amdgcn_mfma_f32_16x16x32_bf16(a1l, b1h, acc[1][1], 0, 0, 0);
    }
    __syncthreads();
  }
#pragma unroll
  for (int r = 0; r < 2; ++r) {
#pragma unroll
    for (int cI = 0; cI < 2; ++cI) {
      const int gn = n0 + wx * 32 + cI * 16 + (lane & 15);
      float sc0 = 0.f, sh0 = 0.f;
      if (EPI == 0) { sc0 = p1[gn] * BN_INV; sh0 = p2[gn]; }
#pragma unroll
      for (int i = 0; i < 4; ++i) {
        const int gm = m0 + wy * 32 + r * 16 + ((lane >> 4) << 2) + i;
        if (gm >= M) continue;
        const float a = acc[r][cI][i];
        if (EPI == 0) {
          Cout[(size_t)gm * ldc + gn] = fmaxf((a + p0[gn]) * sc0 + sh0, 0.f);
        } else if (EPI == 1) {
          Cout[(size_t)gm * ldc + gn] = a + p0[gn];
        } else {
          const int b3 = gm / T49, q = b3 / NS, t = gm - b3 * T49;
          Cout[(size_t)gm * ldc + gn] = a + p1[(size_t)(q * T49 + t) * 384 + gn];
        }
      }
    }
  }
}

// ---------------- fused attention, block = (q,s,t-group of 7) ---------------
__global__ __launch_bounds__(384) void attention_f32(
    const float* __restrict__ proj, const u16* __restrict__ featTh,
    const u16* __restrict__ featTl, u16* __restrict__ atth,
    u16* __restrict__ attl) {
  __shared__ float WqT[64][9];
  __shared__ float WhT[64][51];
  __shared__ float sc[7][64];
  const int bid = blockIdx.x;
  const int qs = bid / 7, tg = bid - 7 * qs;
  const int q = qs / NS, s = qs - NS * q;
  const int tid = threadIdx.x;
  const float* pq = proj + ((size_t)(NS + q) * T49 + tg * 7) * 64;
  const float* ph = proj + (size_t)s * T49 * 64;
  for (int l = tid; l < 7 * 64; l += 384) WqT[l & 63][l >> 6] = pq[l];
  for (int l = tid; l < T49 * 64; l += 384) WhT[l & 63][l >> 6] = ph[l];
  __syncthreads();
  constexpr float C2LOG2E = 2.8853900817779268f;
  if (tid < 343) {
    const int tl = tid / 49, u = tid - 49 * tl;
    float a0 = 0.f, a1 = 0.f, a2 = 0.f, a3 = 0.f;
#pragma unroll
    for (int h = 0; h < 64; h += 4) {
      const float p0 = WqT[h + 0][tl] * WhT[h + 0][u];
      const float p1 = WqT[h + 1][tl] * WhT[h + 1][u];
      const float p2 = WqT[h + 2][tl] * WhT[h + 2][u];
      const float p3 = WqT[h + 3][tl] * WhT[h + 3][u];
      a0 += 1.f - 2.f * __builtin_amdgcn_rcpf(__builtin_amdgcn_exp2f(p0 * C2LOG2E) + 1.f);
      a1 += 1.f - 2.f * __builtin_amdgcn_rcpf(__builtin_amdgcn_exp2f(p1 * C2LOG2E) + 1.f);
      a2 += 1.f - 2.f * __builtin_amdgcn_rcpf(__builtin_amdgcn_exp2f(p2 * C2LOG2E) + 1.f);
      a3 += 1.f - 2.f * __builtin_amdgcn_rcpf(__builtin_amdgcn_exp2f(p3 * C2LOG2E) + 1.f);
    }
    sc[tl][u] = (a0 + a1) + (a2 + a3);
  }
  __syncthreads();
  if (tid < 56) {
    const int t = tid >> 3, g = tid & 7;
    float m = -3.4e38f;
    for (int u = g; u < T49; u += 8) m = fmaxf(m, sc[t][u]);
    m = fmaxf(m, __shfl_xor(m, 4));
    m = fmaxf(m, __shfl_xor(m, 2));
    m = fmaxf(m, __shfl_xor(m, 1));
    float ssum = 0.f;
    for (int u = g; u < T49; u += 8) {
      const float e = __builtin_amdgcn_exp2f((sc[t][u] - m) * LOG2E);
      sc[t][u] = e; ssum += e;
    }
    ssum += __shfl_xor(ssum, 4);
    ssum += __shfl_xor(ssum, 2);
    ssum += __shfl_xor(ssum, 1);
    const float inv = 1.f / ssum;
    for (int u = g; u < T49; u += 8) sc[t][u] *= inv;
  }
  __syncthreads();
  if (tid < 256) {
    const u16* fsh = featTh + (size_t)s * T49 * 256;
    const u16* fsl = featTl + (size_t)s * T49 * 256;
    const size_t obase = ((size_t)qs * T49 + tg * 7) * 256;
    float acc[7] = {0.f, 0.f, 0.f, 0.f, 0.f, 0.f, 0.f};
    for (int u = 0; u < T49; ++u) {
      const float v = b2f(fsh[u * 256 + tid]) + b2f(fsl[u * 256 + tid]);
#pragma unroll
      for (int i = 0; i < 7; ++i) acc[i] += sc[i][u] * v;
    }
#pragma unroll
    for (int i = 0; i < 7; ++i) {
      const float a = acc[i];
      const u16 h = f2b(a);
      atth[obase + (size_t)i * 256 + tid] = h;
      attl[obase + (size_t)i * 256 + tid] = f2b(a - b2f(h));
    }
  }
}

// ---------------- batched MFMA GRU (r16 structure, 53.5us measured) ---------
constexpr int SPB = 8;
__global__ __launch_bounds__(512) void gru_mfma(
    const float* __restrict__ gi,
    const float* __restrict__ wh,
    const float* __restrict__ bh,
    u16* __restrict__ yh, u16* __restrict__ yl,
    float* __restrict__ hfin,
    int store_all) {
  __shared__ u16 hah[16][136];
  __shared__ float ghs[SPB][384];
  __shared__ float hfl[SPB][128];
  const int tid = threadIdx.x;
  const int lane = tid & 63, wv = tid >> 6;
  const int r0 = blockIdx.x * SPB;
  bf16x8v Bhr[3][4], Blr[3][4];
#pragma unroll
  for (int f = 0; f < 3; ++f) {
    const int n = (wv * 3 + f) * 16 + (lane & 15);
#pragma unroll
    for (int kk = 0; kk < 4; ++kk) {
      const int k = kk * 32 + ((lane >> 4) << 3);
      const float* p = wh + (size_t)n * 128 + k;
      float v[8];
      *(float4*)&v[0] = *(const float4*)p;
      *(float4*)&v[4] = *(const float4*)(p + 4);
      u32 hp[4], lp[4];
      split8(v, hp, lp);
      Bhr[f][kk] = *(bf16x8v*)hp;
      Blr[f][kk] = *(bf16x8v*)lp;
    }
  }
  const int row0 = tid >> 7, j0 = tid & 127;
  const int row1 = (512 + tid) >> 7, j1 = tid & 127;
  int sq0 = r0 + row0; if (sq0 >= B3) sq0 = B3 - 1;
  int sq1 = r0 + row1; if (sq1 >= B3) sq1 = B3 - 1;
  const float bhr0 = bh[j0], bhz0 = bh[128 + j0], bhn0 = bh[256 + j0];
  const float bhr1 = bh[j1], bhz1 = bh[128 + j1], bhn1 = bh[256 + j1];
  const float* gib0 = gi + (size_t)sq0 * T49 * 384;
  const float* gib1 = gi + (size_t)sq1 * T49 * 384;
  for (int i = tid; i < 16 * 136; i += 512) hah[i / 136][i % 136] = 0;
  for (int i = tid; i < SPB * 128; i += 512) hfl[i >> 7][i & 127] = 0.f;
  __syncthreads();
  const int ar = lane & 15, ko = (lane >> 4) << 3;
  float xr0c = gib0[j0], xz0c = gib0[128 + j0], xn0c = gib0[256 + j0];
  float xr1c = gib1[j1], xz1c = gib1[128 + j1], xn1c = gib1[256 + j1];
  for (int t = 0; t < T49; ++t) {
    const int tn = (t + 1 < T49) ? t + 1 : t;
    const float* g0n = gib0 + (size_t)tn * 384;
    const float* g1n = gib1 + (size_t)tn * 384;
    const float xr0n = g0n[j0], xz0n = g0n[128 + j0], xn0n = g0n[256 + j0];
    const float xr1n = g1n[j1], xz1n = g1n[128 + j1], xn1n = g1n[256 + j1];
    bf16x8v Ah[4];
#pragma unroll
    for (int kk = 0; kk < 4; ++kk)
      Ah[kk] = *(const bf16x8v*)&hah[ar][kk * 32 + ko];
#pragma unroll
    for (int f = 0; f < 3; ++f) {
      f32x4 acc = {0, 0, 0, 0};
#pragma unroll
      for (int kk = 0; kk < 4; ++kk)
        acc = __builtin_amdgcn_mfma_f32_16x16x32_bf16(Ah[kk], Bhr[f][kk], acc, 0, 0, 0);
#pragma unroll
      for (int kk = 0; kk < 4; ++kk)
        acc = __builtin_amdgcn_mfma_f32_16x16x32_bf16(Ah[kk], Blr[f][kk], acc, 0, 0, 0);
      const int nc = (wv * 3 + f) * 16 + (lane & 15);
      const int rb = (lane >> 4) << 2;
      if (rb < SPB) {
#pragma unroll
        for (int i = 0; i < 4; ++i) ghs[rb + i][nc] = acc[i];
      }
    }
    __syncthreads();
    {
      const float r_ = fsigmoid(xr0c + ghs[row0][j0] + bhr0);
      const float z_ = fsigmoid(xz0c + ghs[row0][128 + j0] + bhz0);
      const float n_ = ftanh(xn0c + r_ * (ghs[row0][256 + j0] + bhn0));
      const float hn = (1.f - z_) * n_ + z_ * hfl[row0][j0];
      hfl[row0][j0] = hn;
      const u16 hb = f2b(hn);
      hah[row0][j0] = hb;
      if (r0 + row0 < B3) {
        if (store_all) {
          const size_t o = ((size_t)(r0 + row0) * T49 + t) * 128 + j0;
          yh[o] = hb;
          yl[o] = f2b(hn - b2f(hb));
        } else if (t == T49 - 1) {
          hfin[(size_t)(r0 + row0) * 128 + j0] = hn;
        }
      }
    }
    {
      const float r_ = fsigmoid(xr1c + ghs[row1][j1] + bhr1);
      const float z_ = fsigmoid(xz1c + ghs[row1][128 + j1] + bhz1);
      const float n_ = ftanh(xn1c + r_ * (ghs[row1][256 + j1] + bhn1));
      const float hn = (1.f - z_) * n_ + z_ * hfl[row1][j1];
      hfl[row1][j1] = hn;
      const u16 hb = f2b(hn);
      hah[row1][j1] = hb;
      if (r0 + row1 < B3) {
        if (store_all) {
          const size_t o = ((size_t)(r0 + row1) * T49 + t) * 128 + j1;
          yh[o] = hb;
          yl[o] = f2b(hn - b2f(hb));
        } else if (t == T49 - 1) {
          hfin[(size_t)(r0 + row1) * 128 + j1] = hn;
        }
      }
    }
    __syncthreads();
    xr0c = xr0n; xz0c = xz0n; xn0c = xn0n;
    xr1c = xr1n; xz1c = xz1n; xn1c = xn1n;
  }
}

// ---------------- head ----------------
__global__ __launch_bounds__(512) void head_kernel(
    const float* __restrict__ hf, const float* __restrict__ tw,
    const float* __restrict__ tb, float* __restrict__ out) {
  __shared__ float lg[B3];
  const int tid = threadIdx.x;
  if (tid < B3) {
    const float* h = hf + (size_t)tid * 128;
    float acc = tb[0];
    for (int k = 0; k < 128; ++k) acc += h[k] * tw[k];
    lg[tid] = acc;
  }
  __syncthreads();
  if (tid < NQ) {
    float cls[5];
#pragma unroll
    for (int n = 0; n < 5; ++n) {
      float s = 0.f;
#pragma unroll
      for (int k = 0; k < 5; ++k) s += lg[tid * 25 + n * 5 + k];
      cls[n] = s;
    }
    float m = cls[0];
#pragma unroll
    for (int n = 1; n < 5; ++n) m = fmaxf(m, cls[n]);
    float se = 0.f;
#pragma unroll
    for (int n = 0; n < 5; ++n) se += expf(cls[n] - m);
    const float lse = m + logf(se);
#pragma unroll
    for (int n = 0; n < 5; ++n) out[tid * 5 + n] = cls[n] - lse;
  }
}

extern "C" void kernel_launch(void* const* d_in, const int* in_sizes, int n_in,
                              void* d_out, int out_size, void* d_ws,
                              size_t ws_size, hipStream_t stream) {
  (void)in_sizes; (void)n_in; (void)out_size; (void)ws_size;
  const float* support = (const float*)d_in[0];
  const float* query   = (const float*)d_in[1];
  const float* cw1 = (const float*)d_in[2];  const float* cb1 = (const float*)d_in[3];
  const float* cw2 = (const float*)d_in[4];  const float* cb2 = (const float*)d_in[5];
  const float* cw3 = (const float*)d_in[6];  const float* cb3 = (const float*)d_in[7];
  const float* cw4 = (const float*)d_in[8];  const float* cb4 = (const float*)d_in[9];
  const float* g1  = (const float*)d_in[10]; const float* be1 = (const float*)d_in[11];
  const float* g2  = (const float*)d_in[12]; const float* be2 = (const float*)d_in[13];
  const float* g3  = (const float*)d_in[14]; const float* be3 = (const float*)d_in[15];
  const float* g4  = (const float*)d_in[16]; const float* be4 = (const float*)d_in[17];
  const float* aw  = (const float*)d_in[18]; const float* ab  = (const float*)d_in[19];
  const float* wi0 = (const float*)d_in[20]; const float* wh0 = (const float*)d_in[21];
  const float* bi0 = (const float*)d_in[22]; const float* bh0 = (const float*)d_in[23];
  const float* wi1 = (const float*)d_in[24]; const float* wh1 = (const float*)d_in[25];
  const float* bi1 = (const float*)d_in[26]; const float* bh1 = (const float*)d_in[27];
  const float* tw  = (const float*)d_in[28]; const float* tb  = (const float*)d_in[29];

  char* ws = (char*)d_ws;
  float* out = (float*)d_out;
  u16* A1H    = (u16*)(ws + A1H_OFF);
  u16* A1L    = (u16*)(ws + A1L_OFF);
  float* X2   = (float*)(ws + X2_OFF);
  u16* P2H    = (u16*)(ws + P2H_OFF);
  u16* P2L    = (u16*)(ws + P2L_OFF);
  float* X3   = (float*)(ws + X3_OFF);
  u16* P3H    = (u16*)(ws + P3H_OFF);
  u16* P3L    = (u16*)(ws + P3L_OFF);
  float* X4   = (float*)(ws + X4_OFF);
  u16* FEATTH = (u16*)(ws + FEATTH_OFF);
  u16* FEATTL = (u16*)(ws + FEATTL_OFF);
  float* PROJ = (float*)(ws + PROJ_OFF);
  float* QG   = (float*)(ws + QG_OFF);
  u16* ATTH   = (u16*)(ws + ATTH_OFF);
  u16* ATTL   = (u16*)(ws + ATTL_OFF);
  float* GI   = (float*)(ws + GI_OFF);
  u16* Y0H    = (u16*)(ws + Y0H_OFF);
  u16* Y0L    = (u16*)(ws + Y0L_OFF);
  float* HFIN = (float*)(ws + HFIN_OFF);
  u16* WBH = (u16*)(ws + WBH_OFF);
  u16* WBL = (u16*)(ws + WBL_OFF);

  // weight conversions (single fused launch; now also emits wi0 halves)
  cvt_all<<<(CVT_N2 + 255) / 256, 256, 0, stream>>>(cw2, cw3, cw4, aw, wi0, wi1, WBH, WBL);

  // ---- encoder ----
  conv1_pool<<<15680, 256, 0, stream>>>(support, query, cw1, cb1, g1, be1, A1H, A1L);
  sgemm<2, 0><<<dim3(1, 1960), 256, 0, stream>>>(
      A1H, A1L, nullptr, nullptr, 125440, 288, WBH + W2_E, WBL + W2_E,
      cb2, g2, be2, X2, 64, 56, 56, 32, 5);
  maxpool2_split<<<1960, 256, 0, stream>>>(X2, P2H, P2L, NB, 56, 56, 64);
  sgemm<2, 0><<<dim3(2, 490), 256, 0, stream>>>(
      P2H, P2L, nullptr, nullptr, 31360, 576, WBH + W3_E, WBL + W3_E,
      cb3, g3, be3, X3, 128, 28, 28, 64, 6);
  maxpool2_split<<<980, 256, 0, stream>>>(X3, P3H, P3L, NB, 28, 28, 128);
  sgemm<2, 0><<<dim3(4, 123), 256, 0, stream>>>(
      P3H, P3L, nullptr, nullptr, 7840, 1152, WBH + W4_E, WBL + W4_E,
      cb4, g4, be4, X4, 256, 14, 14, 128, 7);
  maxpool2_split<<<490, 256, 0, stream>>>(X4, FEATTH, FEATTL, NB, 14, 14, 256);

  // ---- qrep-split precompute: QG[q*49+t][j] = qf . wi0[:,256:] + bi0 ----
  sgemm<0, 1><<<dim3(6, 12), 256, 0, stream>>>(
      FEATTH + (size_t)NS * T49 * 256, FEATTL + (size_t)NS * T49 * 256,
      nullptr, nullptr, NQ * T49, 256, WBH + WI0B_E, WBL + WI0B_E,
      bi0, nullptr, nullptr, QG, 384, 0, 0, 0, 0);

  // ---- attention ----
  sgemm<0, 1><<<dim3(1, 31), 256, 0, stream>>>(
      FEATTH, FEATTL, nullptr, nullptr, NB * T49, 256, WBH + AW_E, WBL + AW_E,
      ab, nullptr, nullptr, PROJ, 64, 0, 0, 0, 0);
  attention_f32<<<B3 * 7, 384, 0, stream>>>(PROJ, FEATTH, FEATTL, ATTH, ATTL);

  // ---- GRU stack (gemm0: K=256 over ATT + QG gather-add epilogue) ----
  sgemm<0, 2><<<dim3(6, 288), 256, 0, stream>>>(
      ATTH, ATTL, nullptr, nullptr, B3 * T49, 256, WBH + WI0A_E, WBL + WI0A_E,
      nullptr, QG, nullptr, GI, 384, 0, 0, 0, 0);
  gru_mfma<<<47, 512, 0, stream>>>(GI, wh0, bh0, Y0H, Y0L, nullptr, 1);
  sgemm<0, 1><<<dim3(6, 288), 256, 0, stream>>>(
      Y0H, Y0L, nullptr, nullptr, B3 * T49, 128, WBH + WI1_E, WBL + WI1_E,
      bi1, nullptr, nullptr, GI, 384, 0, 0, 0, 0);
  gru_mfma<<<47, 512, 0, stream>>>(GI, wh1, bh1, nullptr, nullptr, HFIN, 0);

  // ---- head ----
  head_kernel<<<1, 512, 0, stream>>>(HFIN, tw, tb, out);
}